// Round 1
// baseline (932.077 us; speedup 1.0000x reference)
//
#include <hip/hip_runtime.h>
#include <hip/hip_bf16.h>
#include <math.h>

// Problem constants
#define NBATCH 4
#define TQD 4096
#define TBD 2048
#define CDIM 512
#define NH 8
#define HD 64
#define NINNER 2048

using short8 = __attribute__((ext_vector_type(8))) short;
using f32x4  = __attribute__((ext_vector_type(4))) float;

__device__ __forceinline__ float b2f(short s) {
  return __uint_as_float(((unsigned)(unsigned short)s) << 16);
}
__device__ __forceinline__ short f2b(float f) {
  unsigned u = __float_as_uint(f);
  return (short)((u + 0x7FFFu + ((u >> 16) & 1u)) >> 16);
}

// ---------------- LayerNorm (fp32 in -> bf16 out), one block per row, C=512
__launch_bounds__(256)
__global__ void ln_kernel(const float* __restrict__ x, const float* __restrict__ g,
                          const float* __restrict__ b, short* __restrict__ out)
{
  int r = blockIdx.x;
  int tid = threadIdx.x;
  float2 v = ((const float2*)(x + (size_t)r * CDIM))[tid];
  float s = v.x + v.y, s2 = v.x * v.x + v.y * v.y;
#pragma unroll
  for (int m = 1; m < 64; m <<= 1) { s += __shfl_xor(s, m); s2 += __shfl_xor(s2, m); }
  __shared__ float red[8];
  int wave = tid >> 6;
  if ((tid & 63) == 0) { red[wave] = s; red[4 + wave] = s2; }
  __syncthreads();
  s  = red[0] + red[1] + red[2] + red[3];
  s2 = red[4] + red[5] + red[6] + red[7];
  float mean = s * (1.0f / CDIM);
  float var  = s2 * (1.0f / CDIM) - mean * mean;
  float inv  = rsqrtf(var + 1e-5f);
  float2 gg = ((const float2*)g)[tid];
  float2 bb = ((const float2*)b)[tid];
  short2 o;
  o.x = f2b((v.x - mean) * inv * gg.x + bb.x);
  o.y = f2b((v.y - mean) * inv * gg.y + bb.y);
  *((short2*)(out + (size_t)r * CDIM + 2 * tid)) = o;
}

// ---------------- softmax over each 64-chunk of a 512-wide bf16 row (in place)
__launch_bounds__(256)
__global__ void softmax64_kernel(short* __restrict__ d)
{
  size_t base = (size_t)blockIdx.x * CDIM;
  int tid = threadIdx.x;
  short2 v = *((short2*)(d + base + 2 * tid));
  float a = b2f(v.x), c = b2f(v.y);
  float mx = fmaxf(a, c);
#pragma unroll
  for (int m = 1; m < 32; m <<= 1) mx = fmaxf(mx, __shfl_xor(mx, m));
  float ea = __expf(a - mx), ec = __expf(c - mx);
  float s = ea + ec;
#pragma unroll
  for (int m = 1; m < 32; m <<= 1) s += __shfl_xor(s, m);
  float inv = 1.0f / s;
  v.x = f2b(ea * inv);
  v.y = f2b(ec * inv);
  *((short2*)(d + base + 2 * tid)) = v;
}

// ---------------- transpose + convert weights: W[K][N] f32 -> Wt[N][K] bf16
__launch_bounds__(256)
__global__ void tcvt_kernel(const float* __restrict__ W, short* __restrict__ Wt, int K, int N)
{
  __shared__ float t[32][33];
  int nbk = K >> 5;
  int bk = blockIdx.x % nbk, bn = blockIdx.x / nbk;
  int cx = threadIdx.x & 31, cy = threadIdx.x >> 5;
#pragma unroll
  for (int i = 0; i < 4; i++)
    t[cy + 8 * i][cx] = W[(size_t)(bk * 32 + cy + 8 * i) * N + bn * 32 + cx];
  __syncthreads();
#pragma unroll
  for (int i = 0; i < 4; i++)
    Wt[(size_t)(bn * 32 + cy + 8 * i) * K + bk * 32 + cx] = f2b(t[cx][cy + 8 * i]);
}

// ---------------- main GEMM: C[M][N] = A[M][K] * Bt[N][K]^T + bias (+epilogue)
// A, Bt bf16; acc fp32. 128x128 tile, BK=32, 4 waves (2x2), 4x4 16x16x32 MFMA frags.
#define LDT 40   // padded LDS row stride (shorts); 80B => 16B-aligned rows, 2-way banks
enum { EPI_B_BF16 = 0, EPI_B_GELU_BF16 = 1, EPI_B_RES_F32 = 2 };

template<int EPI>
__launch_bounds__(256)
__global__ void gemm_bt(const short* __restrict__ A, const short* __restrict__ Bt,
                        const float* __restrict__ bias, const float* __restrict__ resid,
                        void* __restrict__ outp, int M, int N, int K)
{
  __shared__ short As[128 * LDT];
  __shared__ short Bs[128 * LDT];
  int tid = threadIdx.x;
  int lane = tid & 63, wave = tid >> 6;
  int l15 = lane & 15, g = lane >> 4;
  int nbn = N >> 7;
  int bm = blockIdx.x / nbn, bn = blockIdx.x % nbn;
  int wr = wave >> 1, wc = wave & 1;
  f32x4 acc[4][4] = {};

  int c0 = tid, c1 = tid + 256;
  const short* pa0 = A  + (size_t)(bm * 128 + (c0 >> 2)) * K + (c0 & 3) * 8;
  const short* pa1 = A  + (size_t)(bm * 128 + (c1 >> 2)) * K + (c1 & 3) * 8;
  const short* pb0 = Bt + (size_t)(bn * 128 + (c0 >> 2)) * K + (c0 & 3) * 8;
  const short* pb1 = Bt + (size_t)(bn * 128 + (c1 >> 2)) * K + (c1 & 3) * 8;
  short* wa0 = As + (c0 >> 2) * LDT + (c0 & 3) * 8;
  short* wa1 = As + (c1 >> 2) * LDT + (c1 & 3) * 8;
  short* wb0 = Bs + (c0 >> 2) * LDT + (c0 & 3) * 8;
  short* wb1 = Bs + (c1 >> 2) * LDT + (c1 & 3) * 8;
  const short* ra = As + (wr * 64 + l15) * LDT + g * 8;
  const short* rb = Bs + (wc * 64 + l15) * LDT + g * 8;

  for (int kt = 0; kt < K; kt += 32) {
    short8 va0 = *(const short8*)(pa0 + kt);
    short8 va1 = *(const short8*)(pa1 + kt);
    short8 vb0 = *(const short8*)(pb0 + kt);
    short8 vb1 = *(const short8*)(pb1 + kt);
    __syncthreads();
    *(short8*)wa0 = va0; *(short8*)wa1 = va1;
    *(short8*)wb0 = vb0; *(short8*)wb1 = vb1;
    __syncthreads();
    short8 af[4], bfr[4];
#pragma unroll
    for (int m = 0; m < 4; m++) af[m] = *(const short8*)(ra + m * 16 * LDT);
#pragma unroll
    for (int n = 0; n < 4; n++) bfr[n] = *(const short8*)(rb + n * 16 * LDT);
#pragma unroll
    for (int m = 0; m < 4; m++)
#pragma unroll
      for (int n = 0; n < 4; n++)
        acc[m][n] = __builtin_amdgcn_mfma_f32_16x16x32_bf16(af[m], bfr[n], acc[m][n], 0, 0, 0);
  }

  int row0 = bm * 128 + wr * 64, col0 = bn * 128 + wc * 64;
#pragma unroll
  for (int m = 0; m < 4; m++) {
#pragma unroll
    for (int n = 0; n < 4; n++) {
      int col = col0 + n * 16 + l15;
      float bz = bias[col];
#pragma unroll
      for (int r = 0; r < 4; r++) {
        int row = row0 + m * 16 + g * 4 + r;
        float vv = acc[m][n][r] + bz;
        if (EPI == EPI_B_GELU_BF16) vv = 0.5f * vv * (1.0f + erff(vv * 0.70710678118f));
        if (EPI == EPI_B_RES_F32) {
          ((float*)outp)[(size_t)row * N + col] = resid[(size_t)row * N + col] + vv;
        } else {
          ((unsigned short*)outp)[(size_t)row * N + col] = (unsigned short)f2b(vv);
        }
      }
    }
  }
}

// ---------------- ctx[bh] = sum_t k[t,:]^T v[t,:]  (64x64 per (b,h)); atomics into zeroed ctx
#define LDC 40
__launch_bounds__(256)
__global__ void ctx_kernel(const short* __restrict__ k, const short* __restrict__ v,
                           float* __restrict__ ctx, int T)
{
  __shared__ short kT[4][64 * LDC];
  __shared__ short vT[4][64 * LDC];
  int bh = blockIdx.x;
  int b = bh >> 3, h = bh & 7;
  int tid = threadIdx.x, lane = tid & 63, wave = tid >> 6;
  int l15 = lane & 15, g = lane >> 4;
  int tlen = T >> 2;
  int tbeg = wave * tlen;
  f32x4 acc[4][4] = {};
  short* myK = kT[wave];
  short* myV = vT[wave];
  for (int t0 = tbeg; t0 < tbeg + tlen; t0 += 32) {
#pragma unroll
    for (int j = 0; j < 4; j++) {
      int c = lane + j * 64;          // 256 chunks of 8 -> 32x64 tile
      int r = c >> 3, d0 = (c & 7) * 8;
      short8 kv = *(const short8*)(k + (size_t)(b * T + t0 + r) * CDIM + h * 64 + d0);
      short8 vv = *(const short8*)(v + (size_t)(b * T + t0 + r) * CDIM + h * 64 + d0);
#pragma unroll
      for (int i = 0; i < 8; i++) {
        myK[(d0 + i) * LDC + r] = kv[i];
        myV[(d0 + i) * LDC + r] = vv[i];
      }
    }
    __syncthreads();
    short8 af[4], bfr[4];
#pragma unroll
    for (int m = 0; m < 4; m++) af[m]  = *(const short8*)(myK + (m * 16 + l15) * LDC + g * 8);
#pragma unroll
    for (int n = 0; n < 4; n++) bfr[n] = *(const short8*)(myV + (n * 16 + l15) * LDC + g * 8);
#pragma unroll
    for (int m = 0; m < 4; m++)
#pragma unroll
      for (int n = 0; n < 4; n++)
        acc[m][n] = __builtin_amdgcn_mfma_f32_16x16x32_bf16(af[m], bfr[n], acc[m][n], 0, 0, 0);
    __syncthreads();
  }
  float* cp = ctx + (size_t)bh * 64 * 64;
#pragma unroll
  for (int m = 0; m < 4; m++)
#pragma unroll
    for (int n = 0; n < 4; n++)
#pragma unroll
      for (int r = 0; r < 4; r++)
        atomicAdd(cp + (m * 16 + g * 4 + r) * 64 + (n * 16 + l15), acc[m][n][r]);
}

// ---------------- column sums of softmaxed k per (b,h): ksum[bh][64]
__launch_bounds__(256)
__global__ void colsum_kernel(const short* __restrict__ k, float* __restrict__ ksum, int T)
{
  int part = blockIdx.x & 7, bh = blockIdx.x >> 3;
  int b = bh >> 3, h = bh & 7;
  int d = threadIdx.x & 63, tq = threadIdx.x >> 6;
  int tlen = T >> 3, t0 = part * tlen;
  float s = 0.0f;
  for (int t = t0 + tq; t < t0 + tlen; t += 4)
    s += b2f(k[(size_t)(b * T + t) * CDIM + h * 64 + d]);
  atomicAdd(&ksum[bh * 64 + d], s);
}

// ---------------- d_inv[br][bh][t] = 1/max(sum_d q[t,d]*ksum[br][bh][d], 1e-9)
__launch_bounds__(256)
__global__ void dinv_kernel(const short* __restrict__ q, const float* __restrict__ ksum,
                            float* __restrict__ dinv, int T, int nb)
{
  int p = blockIdx.x * 4 + (threadIdx.x >> 6);   // over 32*T (bh,t) pairs
  int lane = threadIdx.x & 63;
  int bh = p / T, t = p % T;
  int b = bh >> 3, h = bh & 7;
  float qv = b2f(q[(size_t)(b * T + t) * CDIM + h * 64 + lane]);
  for (int br = 0; br < nb; br++) {
    float s = qv * ksum[(br * 32 + bh) * 64 + lane];
#pragma unroll
    for (int m = 1; m < 64; m <<= 1) s += __shfl_xor(s, m);
    if (lane == 0) dinv[((size_t)br * 32 + bh) * T + t] = 1.0f / fmaxf(s, 1e-9f);
  }
}

// ---------------- out[t,:] = q[t,:] + sum_br dinv[br][t] * (q[t,:] @ ctx[br])
#define LQ 72
__launch_bounds__(256)
__global__ void qctx_kernel(const short* __restrict__ q,
                            const float* __restrict__ ctx,   // [nb][32][64][64]
                            const float* __restrict__ dinv,  // [nb][32][T]
                            short* __restrict__ outp, int T, int nb)
{
  __shared__ short qs[128 * LQ];
  __shared__ short cT[2][64 * LQ];
  __shared__ float dls[2][128];
  int ntb = T >> 7;
  int bh = blockIdx.x / ntb, tq = blockIdx.x % ntb;
  int b = bh >> 3, h = bh & 7;
  int tid = threadIdx.x, lane = tid & 63, wave = tid >> 6;
  int l15 = lane & 15, g = lane >> 4;
  size_t qbase = (size_t)(b * T + tq * 128) * CDIM + h * 64;

#pragma unroll
  for (int j = 0; j < 4; j++) {
    int c = tid + j * 256;            // 1024 chunks of 8 -> 128x64 tile
    int r = c >> 3, d0 = (c & 7) * 8;
    *(short8*)(qs + r * LQ + d0) = *(const short8*)(q + qbase + (size_t)r * CDIM + d0);
  }
  for (int br = 0; br < nb; br++) {
    const float* cp = ctx + ((size_t)br * 32 + bh) * 4096;
#pragma unroll
    for (int j = 0; j < 16; j++) {
      int e2 = tid + j * 256;
      int dd = e2 >> 6, ee = e2 & 63;
      cT[br][ee * LQ + dd] = f2b(cp[e2]);
    }
    if (tid < 128) dls[br][tid] = dinv[((size_t)br * 32 + bh) * T + tq * 128 + tid];
  }
  __syncthreads();

  int r0 = wave * 32;
  short8 af[2][2];
#pragma unroll
  for (int m = 0; m < 2; m++)
#pragma unroll
    for (int kk = 0; kk < 2; kk++)
      af[m][kk] = *(const short8*)(qs + (r0 + m * 16 + l15) * LQ + kk * 32 + g * 8);

  float ofin[2][4][4];
#pragma unroll
  for (int m = 0; m < 2; m++)
#pragma unroll
    for (int n = 0; n < 4; n++)
#pragma unroll
      for (int r = 0; r < 4; r++)
        ofin[m][n][r] = b2f(qs[(r0 + m * 16 + g * 4 + r) * LQ + n * 16 + l15]);

  for (int br = 0; br < nb; br++) {
    f32x4 acc[2][4] = {};
#pragma unroll
    for (int kk = 0; kk < 2; kk++) {
      short8 bfr[4];
#pragma unroll
      for (int n = 0; n < 4; n++)
        bfr[n] = *(const short8*)(cT[br] + (n * 16 + l15) * LQ + kk * 32 + g * 8);
#pragma unroll
      for (int m = 0; m < 2; m++)
#pragma unroll
        for (int n = 0; n < 4; n++)
          acc[m][n] = __builtin_amdgcn_mfma_f32_16x16x32_bf16(af[m][kk], bfr[n], acc[m][n], 0, 0, 0);
    }
#pragma unroll
    for (int m = 0; m < 2; m++)
#pragma unroll
      for (int n = 0; n < 4; n++)
#pragma unroll
        for (int r = 0; r < 4; r++)
          ofin[m][n][r] += dls[br][r0 + m * 16 + g * 4 + r] * acc[m][n][r];
  }

#pragma unroll
  for (int m = 0; m < 2; m++)
#pragma unroll
    for (int n = 0; n < 4; n++)
#pragma unroll
      for (int r = 0; r < 4; r++) {
        int row = r0 + m * 16 + g * 4 + r;
        int col = n * 16 + l15;
        outp[qbase + (size_t)row * CDIM + col] = f2b(ofin[m][n][r]);
      }
}

extern "C" void kernel_launch(void* const* d_in, const int* in_sizes, int n_in,
                              void* d_out, int out_size, void* d_ws, size_t ws_size,
                              hipStream_t stream)
{
  (void)in_sizes; (void)n_in; (void)out_size; (void)ws_size;
  const float* x     = (const float*)d_in[0];
  const float* y0    = (const float*)d_in[1];
  const float* y1    = (const float*)d_in[2];
  const float* ln1g  = (const float*)d_in[3];
  const float* ln1b  = (const float*)d_in[4];
  const float* ln20g = (const float*)d_in[5];
  const float* ln20b = (const float*)d_in[6];
  const float* ln21g = (const float*)d_in[7];
  const float* ln21b = (const float*)d_in[8];
  const float* ln3g  = (const float*)d_in[9];
  const float* ln3b  = (const float*)d_in[10];
  const float* ln4g  = (const float*)d_in[11];
  const float* ln4b  = (const float*)d_in[12];
  const float* ln5g  = (const float*)d_in[13];
  const float* ln5b  = (const float*)d_in[14];
  const float* caqw  = (const float*)d_in[15];
  const float* caqb  = (const float*)d_in[16];
  const float* cak0w = (const float*)d_in[17];
  const float* cak0b = (const float*)d_in[18];
  const float* cav0w = (const float*)d_in[19];
  const float* cav0b = (const float*)d_in[20];
  const float* cak1w = (const float*)d_in[21];
  const float* cak1b = (const float*)d_in[22];
  const float* cav1w = (const float*)d_in[23];
  const float* cav1b = (const float*)d_in[24];
  const float* capw  = (const float*)d_in[25];
  const float* capb  = (const float*)d_in[26];
  const float* saqw  = (const float*)d_in[27];
  const float* saqb  = (const float*)d_in[28];
  const float* sakw  = (const float*)d_in[29];
  const float* sakb  = (const float*)d_in[30];
  const float* savw  = (const float*)d_in[31];
  const float* savb  = (const float*)d_in[32];
  const float* sapw  = (const float*)d_in[33];
  const float* sapb  = (const float*)d_in[34];
  const float* m1w1  = (const float*)d_in[35];
  const float* m1b1  = (const float*)d_in[36];
  const float* m1w2  = (const float*)d_in[37];
  const float* m1b2  = (const float*)d_in[38];
  const float* m2w1  = (const float*)d_in[39];
  const float* m2b1  = (const float*)d_in[40];
  const float* m2w2  = (const float*)d_in[41];
  const float* m2b2  = (const float*)d_in[42];
  float* xout = (float*)d_out;

  char* p = (char*)d_ws;
  size_t off = 0;
  auto take = [&](size_t bytes) {
    char* r = p + off;
    off += (bytes + 255) & ~(size_t)255;
    return r;
  };
  const size_t W512 = (size_t)512 * 512 * 2;
  const size_t WMLP = (size_t)2048 * 512 * 2;
  short* wt_caq  = (short*)take(W512);
  short* wt_cak0 = (short*)take(W512);
  short* wt_cav0 = (short*)take(W512);
  short* wt_cak1 = (short*)take(W512);
  short* wt_cav1 = (short*)take(W512);
  short* wt_cap  = (short*)take(W512);
  short* wt_saq  = (short*)take(W512);
  short* wt_sak  = (short*)take(W512);
  short* wt_sav  = (short*)take(W512);
  short* wt_sap  = (short*)take(W512);
  short* wt_m1w1 = (short*)take(WMLP);
  short* wt_m1w2 = (short*)take(WMLP);
  short* wt_m2w1 = (short*)take(WMLP);
  short* wt_m2w2 = (short*)take(WMLP);
  const size_t ACT = (size_t)16384 * 512 * 2;
  short* xn   = (short*)take(ACT);
  short* bufA = (short*)take(ACT);   // q
  short* bufB = (short*)take(ACT);   // k
  short* bufC = (short*)take(ACT);   // v
  short* bufD = (short*)take(ACT);   // yn / attn-out
  short* h1   = (short*)take((size_t)16384 * 2048 * 2);
  float* ksum  = (float*)take((size_t)2 * 32 * 64 * 4);
  float* ctxb  = (float*)take((size_t)2 * 32 * 64 * 64 * 4);
  float* dinvb = (float*)take((size_t)2 * 32 * 4096 * 4);

  const int MQ  = NBATCH * TQD;   // 16384
  const int MKV = NBATCH * TBD;   // 8192

  // ---- weight transpose+convert ----
  tcvt_kernel<<<256, 256, 0, stream>>>(caqw,  wt_caq,  512, 512);
  tcvt_kernel<<<256, 256, 0, stream>>>(cak0w, wt_cak0, 512, 512);
  tcvt_kernel<<<256, 256, 0, stream>>>(cav0w, wt_cav0, 512, 512);
  tcvt_kernel<<<256, 256, 0, stream>>>(cak1w, wt_cak1, 512, 512);
  tcvt_kernel<<<256, 256, 0, stream>>>(cav1w, wt_cav1, 512, 512);
  tcvt_kernel<<<256, 256, 0, stream>>>(capw,  wt_cap,  512, 512);
  tcvt_kernel<<<256, 256, 0, stream>>>(saqw,  wt_saq,  512, 512);
  tcvt_kernel<<<256, 256, 0, stream>>>(sakw,  wt_sak,  512, 512);
  tcvt_kernel<<<256, 256, 0, stream>>>(savw,  wt_sav,  512, 512);
  tcvt_kernel<<<256, 256, 0, stream>>>(sapw,  wt_sap,  512, 512);
  tcvt_kernel<<<1024, 256, 0, stream>>>(m1w1, wt_m1w1, 512, 2048);
  tcvt_kernel<<<1024, 256, 0, stream>>>(m1w2, wt_m1w2, 2048, 512);
  tcvt_kernel<<<1024, 256, 0, stream>>>(m2w1, wt_m2w1, 512, 2048);
  tcvt_kernel<<<1024, 256, 0, stream>>>(m2w2, wt_m2w2, 2048, 512);

  // ---- cross-attention ----
  ln_kernel<<<MQ, 256, 0, stream>>>(x, ln1g, ln1b, xn);
  gemm_bt<EPI_B_BF16><<<512, 256, 0, stream>>>(xn, wt_caq, caqb, nullptr, bufA, MQ, 512, 512);
  softmax64_kernel<<<MQ, 256, 0, stream>>>(bufA);
  hipMemsetAsync(ksum, 0, (size_t)2 * 32 * 64 * 4, stream);
  hipMemsetAsync(ctxb, 0, (size_t)2 * 32 * 64 * 64 * 4, stream);
  for (int br = 0; br < 2; br++) {
    const float* yy  = br ? y1 : y0;
    const float* lg  = br ? ln21g : ln20g;
    const float* lb  = br ? ln21b : ln20b;
    const short* wk  = br ? wt_cak1 : wt_cak0;
    const float* bk  = br ? cak1b : cak0b;
    const short* wv  = br ? wt_cav1 : wt_cav0;
    const float* bv  = br ? cav1b : cav0b;
    ln_kernel<<<MKV, 256, 0, stream>>>(yy, lg, lb, bufD);
    gemm_bt<EPI_B_BF16><<<256, 256, 0, stream>>>(bufD, wk, bk, nullptr, bufB, MKV, 512, 512);
    softmax64_kernel<<<MKV, 256, 0, stream>>>(bufB);
    gemm_bt<EPI_B_BF16><<<256, 256, 0, stream>>>(bufD, wv, bv, nullptr, bufC, MKV, 512, 512);
    colsum_kernel<<<256, 256, 0, stream>>>(bufB, ksum + (size_t)br * 2048, TBD);
    ctx_kernel<<<32, 256, 0, stream>>>(bufB, bufC, ctxb + (size_t)br * 32 * 4096, TBD);
  }
  dinv_kernel<<<32 * TQD / 4, 256, 0, stream>>>(bufA, ksum, dinvb, TQD, 2);
  qctx_kernel<<<32 * (TQD / 128), 256, 0, stream>>>(bufA, ctxb, dinvb, bufD, TQD, 2);
  gemm_bt<EPI_B_RES_F32><<<512, 256, 0, stream>>>(bufD, wt_cap, capb, x, xout, MQ, 512, 512);

  // ---- MLP 1 ----
  ln_kernel<<<MQ, 256, 0, stream>>>(xout, ln3g, ln3b, xn);
  gemm_bt<EPI_B_GELU_BF16><<<2048, 256, 0, stream>>>(xn, wt_m1w1, m1b1, nullptr, h1, MQ, 2048, 512);
  gemm_bt<EPI_B_RES_F32><<<512, 256, 0, stream>>>(h1, wt_m1w2, m1b2, xout, xout, MQ, 512, 2048);

  // ---- self-attention ----
  ln_kernel<<<MQ, 256, 0, stream>>>(xout, ln4g, ln4b, xn);
  gemm_bt<EPI_B_BF16><<<512, 256, 0, stream>>>(xn, wt_saq, saqb, nullptr, bufA, MQ, 512, 512);
  softmax64_kernel<<<MQ, 256, 0, stream>>>(bufA);
  gemm_bt<EPI_B_BF16><<<512, 256, 0, stream>>>(xn, wt_sak, sakb, nullptr, bufB, MQ, 512, 512);
  softmax64_kernel<<<MQ, 256, 0, stream>>>(bufB);
  gemm_bt<EPI_B_BF16><<<512, 256, 0, stream>>>(xn, wt_sav, savb, nullptr, bufC, MQ, 512, 512);
  hipMemsetAsync(ksum, 0, (size_t)32 * 64 * 4, stream);
  hipMemsetAsync(ctxb, 0, (size_t)32 * 64 * 64 * 4, stream);
  colsum_kernel<<<256, 256, 0, stream>>>(bufB, ksum, TQD);
  ctx_kernel<<<32, 256, 0, stream>>>(bufB, bufC, ctxb, TQD);
  dinv_kernel<<<32 * TQD / 4, 256, 0, stream>>>(bufA, ksum, dinvb, TQD, 1);
  qctx_kernel<<<32 * (TQD / 128), 256, 0, stream>>>(bufA, ctxb, dinvb, bufD, TQD, 1);
  gemm_bt<EPI_B_RES_F32><<<512, 256, 0, stream>>>(bufD, wt_sap, sapb, xout, xout, MQ, 512, 512);

  // ---- MLP 2 ----
  ln_kernel<<<MQ, 256, 0, stream>>>(xout, ln5g, ln5b, xn);
  gemm_bt<EPI_B_GELU_BF16><<<2048, 256, 0, stream>>>(xn, wt_m2w1, m2b1, nullptr, h1, MQ, 2048, 512);
  gemm_bt<EPI_B_RES_F32><<<512, 256, 0, stream>>>(h1, wt_m2w2, m2b2, xout, xout, MQ, 512, 2048);
}

// Round 2
// 758.876 us; speedup vs baseline: 1.2282x; 1.2282x over previous
//
#include <hip/hip_runtime.h>
#include <hip/hip_bf16.h>
#include <math.h>

// Problem constants
#define NBATCH 4
#define TQD 4096
#define TBD 2048
#define CDIM 512
#define NH 8
#define HD 64
#define NINNER 2048

using short8 = __attribute__((ext_vector_type(8))) short;
using f32x4  = __attribute__((ext_vector_type(4))) float;

__device__ __forceinline__ float b2f(short s) {
  return __uint_as_float(((unsigned)(unsigned short)s) << 16);
}
__device__ __forceinline__ short f2b(float f) {
  unsigned u = __float_as_uint(f);
  return (short)((u + 0x7FFFu + ((u >> 16) & 1u)) >> 16);
}
__device__ __forceinline__ void gload16(const short* g, short* l) {
  __builtin_amdgcn_global_load_lds((const __attribute__((address_space(1))) void*)g,
                                   (__attribute__((address_space(3))) void*)l, 16, 0, 0);
}

// ---------------- LayerNorm (fp32 in -> bf16 out), one block per row, C=512
__launch_bounds__(256)
__global__ void ln_kernel(const float* __restrict__ x, const float* __restrict__ g,
                          const float* __restrict__ b, short* __restrict__ out)
{
  int r = blockIdx.x;
  int tid = threadIdx.x;
  float2 v = ((const float2*)(x + (size_t)r * CDIM))[tid];
  float s = v.x + v.y, s2 = v.x * v.x + v.y * v.y;
#pragma unroll
  for (int m = 1; m < 64; m <<= 1) { s += __shfl_xor(s, m); s2 += __shfl_xor(s2, m); }
  __shared__ float red[8];
  int wave = tid >> 6;
  if ((tid & 63) == 0) { red[wave] = s; red[4 + wave] = s2; }
  __syncthreads();
  s  = red[0] + red[1] + red[2] + red[3];
  s2 = red[4] + red[5] + red[6] + red[7];
  float mean = s * (1.0f / CDIM);
  float var  = s2 * (1.0f / CDIM) - mean * mean;
  float inv  = rsqrtf(var + 1e-5f);
  float2 gg = ((const float2*)g)[tid];
  float2 bb = ((const float2*)b)[tid];
  short2 o;
  o.x = f2b((v.x - mean) * inv * gg.x + bb.x);
  o.y = f2b((v.y - mean) * inv * gg.y + bb.y);
  *((short2*)(out + (size_t)r * CDIM + 2 * tid)) = o;
}

// ---------------- batched transpose+convert: W[K][N] f32 -> Wt[N][K] bf16
struct TcvtDesc {
  const float* src[14];
  short* dst[14];
  int K[14], N[14], nblk[14];
};
__launch_bounds__(256)
__global__ void tcvt_all(TcvtDesc d)
{
  int blk = blockIdx.x, wi = 0;
  while (blk >= d.nblk[wi]) { blk -= d.nblk[wi]; wi++; }
  const float* __restrict__ W = d.src[wi];
  short* __restrict__ Wt = d.dst[wi];
  int K = d.K[wi], N = d.N[wi];
  __shared__ float t[32][33];
  int nbk = K >> 5;
  int bk = blk % nbk, bn = blk / nbk;
  int cx = threadIdx.x & 31, cy = threadIdx.x >> 5;
#pragma unroll
  for (int i = 0; i < 4; i++)
    t[cy + 8 * i][cx] = W[(size_t)(bk * 32 + cy + 8 * i) * N + bn * 32 + cx];
  __syncthreads();
#pragma unroll
  for (int i = 0; i < 4; i++)
    Wt[(size_t)(bn * 32 + cy + 8 * i) * K + bk * 32 + cx] = f2b(t[cx][cy + 8 * i]);
}

// ---------------- main GEMM (m97 structure): C[M][N] = A[M][K]*Bt[N][K]^T + bias
// global_load_lds width=16 into LINEAR LDS [128][32]; 128x128 tile, BK=32,
// 4 waves (2x2), 4x4 16x16x32 MFMA frags, fp32 acc.
enum { EPI_B_BF16 = 0, EPI_B_GELU_BF16 = 1, EPI_B_RES_F32 = 2, EPI_B_SM_BF16 = 3 };

template<int EPI>
__launch_bounds__(256)
__global__ void gemm_bt(const short* __restrict__ A, const short* __restrict__ Bt,
                        const float* __restrict__ bias, const float* __restrict__ resid,
                        void* __restrict__ outp, int M, int N, int K)
{
  __shared__ short As[128 * 32];
  __shared__ short Bs[128 * 32];
  int tid = threadIdx.x;
  int lane = tid & 63, wave = tid >> 6;
  int l15 = lane & 15, g = lane >> 4;
  int nbn = N >> 7;
  int bm = blockIdx.x / nbn, bn = blockIdx.x % nbn;
  int wr = wave >> 1, wc = wave & 1;
  f32x4 acc[4][4] = {};

  // staging: wave w stages chunks {w, w+4} of A and of B (1KiB each:
  // chunk c = LDS bytes [c*1024,(c+1)*1024) = rows [c*16, c*16+16);
  // lane i -> row c*16 + i/4, col (i&3)*8 shorts). LDS dest must be linear.
  const short* gA0 = A  + (size_t)(bm * 128 + wave * 16 + (lane >> 2)) * K + (lane & 3) * 8;
  const short* gB0 = Bt + (size_t)(bn * 128 + wave * 16 + (lane >> 2)) * K + (lane & 3) * 8;
  const short* gA1 = gA0 + (size_t)64 * K;
  const short* gB1 = gB0 + (size_t)64 * K;
  short* lA0 = As + wave * 512;
  short* lA1 = As + wave * 512 + 2048;
  short* lB0 = Bs + wave * 512;
  short* lB1 = Bs + wave * 512 + 2048;
  const short* ra = As + (wr * 64 + l15) * 32 + g * 8;
  const short* rb = Bs + (wc * 64 + l15) * 32 + g * 8;

  for (int kt = 0; kt < K; kt += 32) {
    __syncthreads();
    gload16(gA0 + kt, lA0);
    gload16(gA1 + kt, lA1);
    gload16(gB0 + kt, lB0);
    gload16(gB1 + kt, lB1);
    __syncthreads();
    short8 af[4], bfr[4];
#pragma unroll
    for (int m = 0; m < 4; m++) af[m]  = *(const short8*)(ra + m * 16 * 32);
#pragma unroll
    for (int n = 0; n < 4; n++) bfr[n] = *(const short8*)(rb + n * 16 * 32);
#pragma unroll
    for (int m = 0; m < 4; m++)
#pragma unroll
      for (int n = 0; n < 4; n++)
        acc[m][n] = __builtin_amdgcn_mfma_f32_16x16x32_bf16(af[m], bfr[n], acc[m][n], 0, 0, 0);
  }

  int row0 = bm * 128 + wr * 64, col0 = bn * 128 + wc * 64;
  // bias
#pragma unroll
  for (int n = 0; n < 4; n++) {
    float bz = bias[col0 + n * 16 + l15];
#pragma unroll
    for (int m = 0; m < 4; m++)
#pragma unroll
      for (int r = 0; r < 4; r++)
        acc[m][n][r] += bz;
  }
  if (EPI == EPI_B_SM_BF16) {
    // softmax over each 64-col head chunk: spans n=0..3 x l15 (same wave)
#pragma unroll
    for (int m = 0; m < 4; m++)
#pragma unroll
      for (int r = 0; r < 4; r++) {
        float mx = fmaxf(fmaxf(acc[m][0][r], acc[m][1][r]),
                         fmaxf(acc[m][2][r], acc[m][3][r]));
#pragma unroll
        for (int msk = 1; msk < 16; msk <<= 1) mx = fmaxf(mx, __shfl_xor(mx, msk));
        float e0 = __expf(acc[m][0][r] - mx), e1 = __expf(acc[m][1][r] - mx);
        float e2 = __expf(acc[m][2][r] - mx), e3 = __expf(acc[m][3][r] - mx);
        float s = e0 + e1 + e2 + e3;
#pragma unroll
        for (int msk = 1; msk < 16; msk <<= 1) s += __shfl_xor(s, msk);
        float inv = 1.0f / s;
        acc[m][0][r] = e0 * inv; acc[m][1][r] = e1 * inv;
        acc[m][2][r] = e2 * inv; acc[m][3][r] = e3 * inv;
      }
  }
#pragma unroll
  for (int m = 0; m < 4; m++) {
#pragma unroll
    for (int n = 0; n < 4; n++) {
      int col = col0 + n * 16 + l15;
#pragma unroll
      for (int r = 0; r < 4; r++) {
        int row = row0 + m * 16 + g * 4 + r;
        float vv = acc[m][n][r];
        if (EPI == EPI_B_GELU_BF16) vv = 0.5f * vv * (1.0f + erff(vv * 0.70710678118f));
        if (EPI == EPI_B_RES_F32) {
          ((float*)outp)[(size_t)row * N + col] = resid[(size_t)row * N + col] + vv;
        } else {
          ((unsigned short*)outp)[(size_t)row * N + col] = (unsigned short)f2b(vv);
        }
      }
    }
  }
}

// ---------------- ctx += k^T v per (b,h); grid = 32*parts, atomics into zeroed ctx
#define LDC 40
__launch_bounds__(256)
__global__ void ctx_kernel(const short* __restrict__ k, const short* __restrict__ v,
                           float* __restrict__ ctx, int T, int parts)
{
  __shared__ short kT[4][64 * LDC];
  __shared__ short vT[4][64 * LDC];
  int bh = blockIdx.x & 31, part = blockIdx.x >> 5;
  int b = bh >> 3, h = bh & 7;
  int tid = threadIdx.x, lane = tid & 63, wave = tid >> 6;
  int l15 = lane & 15, g = lane >> 4;
  int tlen = T / (4 * parts);
  int tbeg = (part * 4 + wave) * tlen;
  f32x4 acc[4][4] = {};
  short* myK = kT[wave];
  short* myV = vT[wave];
  for (int t0 = tbeg; t0 < tbeg + tlen; t0 += 32) {
#pragma unroll
    for (int j = 0; j < 4; j++) {
      int c = lane + j * 64;          // 256 chunks of 8 -> 32x64 tile
      int r = c >> 3, d0 = (c & 7) * 8;
      short8 kv = *(const short8*)(k + (size_t)(b * T + t0 + r) * CDIM + h * 64 + d0);
      short8 vv = *(const short8*)(v + (size_t)(b * T + t0 + r) * CDIM + h * 64 + d0);
#pragma unroll
      for (int i = 0; i < 8; i++) {
        myK[(d0 + i) * LDC + r] = kv[i];
        myV[(d0 + i) * LDC + r] = vv[i];
      }
    }
    __syncthreads();
    short8 af[4], bfr[4];
#pragma unroll
    for (int m = 0; m < 4; m++) af[m]  = *(const short8*)(myK + (m * 16 + l15) * LDC + g * 8);
#pragma unroll
    for (int n = 0; n < 4; n++) bfr[n] = *(const short8*)(myV + (n * 16 + l15) * LDC + g * 8);
#pragma unroll
    for (int m = 0; m < 4; m++)
#pragma unroll
      for (int n = 0; n < 4; n++)
        acc[m][n] = __builtin_amdgcn_mfma_f32_16x16x32_bf16(af[m], bfr[n], acc[m][n], 0, 0, 0);
    __syncthreads();
  }
  float* cp = ctx + (size_t)bh * 64 * 64;
#pragma unroll
  for (int m = 0; m < 4; m++)
#pragma unroll
    for (int n = 0; n < 4; n++)
#pragma unroll
      for (int r = 0; r < 4; r++)
        atomicAdd(cp + (m * 16 + g * 4 + r) * 64 + (n * 16 + l15), acc[m][n][r]);
}

// ---------------- column sums of softmaxed k per (b,h): ksum[bh][64]
__launch_bounds__(256)
__global__ void colsum_kernel(const short* __restrict__ k, float* __restrict__ ksum, int T)
{
  int part = blockIdx.x & 7, bh = blockIdx.x >> 3;
  int b = bh >> 3, h = bh & 7;
  int d = threadIdx.x & 63, tq = threadIdx.x >> 6;
  int tlen = T >> 3, t0 = part * tlen;
  float s = 0.0f;
  for (int t = t0 + tq; t < t0 + tlen; t += 4)
    s += b2f(k[(size_t)(b * T + t) * CDIM + h * 64 + d]);
  atomicAdd(&ksum[bh * 64 + d], s);
}

// ---------------- out[t,:] = q[t,:] + sum_br dinv(t) * (q[t,:] @ ctx[br]);
// d_inv computed in-kernel from ksum.
#define LQ 72
__launch_bounds__(256)
__global__ void qctx_kernel(const short* __restrict__ q,
                            const float* __restrict__ ctx,   // [nb][32][64][64]
                            const float* __restrict__ ksum,  // [nb][32][64]
                            short* __restrict__ outp, int T, int nb)
{
  __shared__ short qs[128 * LQ];
  __shared__ short cT[2][64 * LQ];
  __shared__ float dls[2][128];
  int ntb = T >> 7;
  int bh = blockIdx.x / ntb, tq = blockIdx.x % ntb;
  int b = bh >> 3, h = bh & 7;
  int tid = threadIdx.x, lane = tid & 63, wave = tid >> 6;
  int l15 = lane & 15, g = lane >> 4;
  size_t qbase = (size_t)(b * T + tq * 128) * CDIM + h * 64;

#pragma unroll
  for (int j = 0; j < 4; j++) {
    int c = tid + j * 256;            // 1024 chunks of 8 -> 128x64 tile
    int r = c >> 3, d0 = (c & 7) * 8;
    *(short8*)(qs + r * LQ + d0) = *(const short8*)(q + qbase + (size_t)r * CDIM + d0);
  }
  for (int br = 0; br < nb; br++) {
    const float* cp = ctx + ((size_t)br * 32 + bh) * 4096;
#pragma unroll
    for (int j = 0; j < 16; j++) {
      int e2 = tid + j * 256;
      int dd = e2 >> 6, ee = e2 & 63;
      cT[br][ee * LQ + dd] = f2b(cp[e2]);
    }
  }
  __syncthreads();

  int r0 = wave * 32;
  // fused d_inv: 2 lanes per row, 32 d each
  for (int br = 0; br < nb; br++) {
    int row = r0 + (lane >> 1);
    int dbase = (lane & 1) * 32;
    const float* kp = ksum + ((size_t)br * 32 + bh) * 64 + dbase;
    float s = 0.0f;
#pragma unroll
    for (int d = 0; d < 32; d++)
      s += b2f(qs[row * LQ + dbase + d]) * kp[d];
    s += __shfl_xor(s, 1);
    if (!(lane & 1)) dls[br][row] = 1.0f / fmaxf(s, 1e-9f);
  }

  short8 af[2][2];
#pragma unroll
  for (int m = 0; m < 2; m++)
#pragma unroll
    for (int kk = 0; kk < 2; kk++)
      af[m][kk] = *(const short8*)(qs + (r0 + m * 16 + l15) * LQ + kk * 32 + g * 8);

  float ofin[2][4][4];
#pragma unroll
  for (int m = 0; m < 2; m++)
#pragma unroll
    for (int n = 0; n < 4; n++)
#pragma unroll
      for (int r = 0; r < 4; r++)
        ofin[m][n][r] = b2f(qs[(r0 + m * 16 + g * 4 + r) * LQ + n * 16 + l15]);

  for (int br = 0; br < nb; br++) {
    f32x4 acc[2][4] = {};
#pragma unroll
    for (int kk = 0; kk < 2; kk++) {
      short8 bfr[4];
#pragma unroll
      for (int n = 0; n < 4; n++)
        bfr[n] = *(const short8*)(cT[br] + (n * 16 + l15) * LQ + kk * 32 + g * 8);
#pragma unroll
      for (int m = 0; m < 2; m++)
#pragma unroll
        for (int n = 0; n < 4; n++)
          acc[m][n] = __builtin_amdgcn_mfma_f32_16x16x32_bf16(af[m][kk], bfr[n], acc[m][n], 0, 0, 0);
    }
#pragma unroll
    for (int m = 0; m < 2; m++)
#pragma unroll
      for (int n = 0; n < 4; n++)
#pragma unroll
        for (int r = 0; r < 4; r++)
          ofin[m][n][r] += dls[br][r0 + m * 16 + g * 4 + r] * acc[m][n][r];
  }

#pragma unroll
  for (int m = 0; m < 2; m++)
#pragma unroll
    for (int n = 0; n < 4; n++)
#pragma unroll
      for (int r = 0; r < 4; r++) {
        int row = r0 + m * 16 + g * 4 + r;
        int col = n * 16 + l15;
        outp[qbase + (size_t)row * CDIM + col] = f2b(ofin[m][n][r]);
      }
}

extern "C" void kernel_launch(void* const* d_in, const int* in_sizes, int n_in,
                              void* d_out, int out_size, void* d_ws, size_t ws_size,
                              hipStream_t stream)
{
  (void)in_sizes; (void)n_in; (void)out_size; (void)ws_size;
  const float* x     = (const float*)d_in[0];
  const float* y0    = (const float*)d_in[1];
  const float* y1    = (const float*)d_in[2];
  const float* ln1g  = (const float*)d_in[3];
  const float* ln1b  = (const float*)d_in[4];
  const float* ln20g = (const float*)d_in[5];
  const float* ln20b = (const float*)d_in[6];
  const float* ln21g = (const float*)d_in[7];
  const float* ln21b = (const float*)d_in[8];
  const float* ln3g  = (const float*)d_in[9];
  const float* ln3b  = (const float*)d_in[10];
  const float* ln4g  = (const float*)d_in[11];
  const float* ln4b  = (const float*)d_in[12];
  const float* ln5g  = (const float*)d_in[13];
  const float* ln5b  = (const float*)d_in[14];
  const float* caqw  = (const float*)d_in[15];
  const float* caqb  = (const float*)d_in[16];
  const float* cak0w = (const float*)d_in[17];
  const float* cak0b = (const float*)d_in[18];
  const float* cav0w = (const float*)d_in[19];
  const float* cav0b = (const float*)d_in[20];
  const float* cak1w = (const float*)d_in[21];
  const float* cak1b = (const float*)d_in[22];
  const float* cav1w = (const float*)d_in[23];
  const float* cav1b = (const float*)d_in[24];
  const float* capw  = (const float*)d_in[25];
  const float* capb  = (const float*)d_in[26];
  const float* saqw  = (const float*)d_in[27];
  const float* saqb  = (const float*)d_in[28];
  const float* sakw  = (const float*)d_in[29];
  const float* sakb  = (const float*)d_in[30];
  const float* savw  = (const float*)d_in[31];
  const float* savb  = (const float*)d_in[32];
  const float* sapw  = (const float*)d_in[33];
  const float* sapb  = (const float*)d_in[34];
  const float* m1w1  = (const float*)d_in[35];
  const float* m1b1  = (const float*)d_in[36];
  const float* m1w2  = (const float*)d_in[37];
  const float* m1b2  = (const float*)d_in[38];
  const float* m2w1  = (const float*)d_in[39];
  const float* m2b1  = (const float*)d_in[40];
  const float* m2w2  = (const float*)d_in[41];
  const float* m2b2  = (const float*)d_in[42];
  float* xout = (float*)d_out;

  char* p = (char*)d_ws;
  size_t off = 0;
  auto take = [&](size_t bytes) {
    char* r = p + off;
    off += (bytes + 255) & ~(size_t)255;
    return r;
  };
  const size_t W512 = (size_t)512 * 512 * 2;
  const size_t WMLP = (size_t)2048 * 512 * 2;
  short* wt_caq  = (short*)take(W512);
  short* wt_cak0 = (short*)take(W512);
  short* wt_cav0 = (short*)take(W512);
  short* wt_cak1 = (short*)take(W512);
  short* wt_cav1 = (short*)take(W512);
  short* wt_cap  = (short*)take(W512);
  short* wt_saq  = (short*)take(W512);
  short* wt_sak  = (short*)take(W512);
  short* wt_sav  = (short*)take(W512);
  short* wt_sap  = (short*)take(W512);
  short* wt_m1w1 = (short*)take(WMLP);
  short* wt_m1w2 = (short*)take(WMLP);
  short* wt_m2w1 = (short*)take(WMLP);
  short* wt_m2w2 = (short*)take(WMLP);
  const size_t ACT = (size_t)16384 * 512 * 2;
  short* xn   = (short*)take(ACT);
  short* bufA = (short*)take(ACT);   // q
  short* bufB = (short*)take(ACT);   // k
  short* bufC = (short*)take(ACT);   // v
  short* bufD = (short*)take(ACT);   // yn / attn-out
  short* h1   = (short*)take((size_t)16384 * 2048 * 2);
  float* ksum  = (float*)take((size_t)2 * 32 * 64 * 4);
  float* ctxb  = (float*)take((size_t)2 * 32 * 64 * 64 * 4);

  const int MQ  = NBATCH * TQD;   // 16384
  const int MKV = NBATCH * TBD;   // 8192

  // ---- weight transpose+convert (single batched launch) ----
  {
    TcvtDesc d;
    const float* srcs[14] = {caqw, cak0w, cav0w, cak1w, cav1w, capw,
                             saqw, sakw, savw, sapw, m1w1, m1w2, m2w1, m2w2};
    short* dsts[14] = {wt_caq, wt_cak0, wt_cav0, wt_cak1, wt_cav1, wt_cap,
                       wt_saq, wt_sak, wt_sav, wt_sap, wt_m1w1, wt_m1w2, wt_m2w1, wt_m2w2};
    int Ks[14] = {512,512,512,512,512,512,512,512,512,512, 512,2048,512,2048};
    int Ns[14] = {512,512,512,512,512,512,512,512,512,512, 2048,512,2048,512};
    int total = 0;
    for (int i = 0; i < 14; i++) {
      d.src[i] = srcs[i]; d.dst[i] = dsts[i]; d.K[i] = Ks[i]; d.N[i] = Ns[i];
      d.nblk[i] = (Ks[i] >> 5) * (Ns[i] >> 5);
      total += d.nblk[i];
    }
    tcvt_all<<<total, 256, 0, stream>>>(d);
  }

  // ---- cross-attention ----
  ln_kernel<<<MQ, 256, 0, stream>>>(x, ln1g, ln1b, xn);
  gemm_bt<EPI_B_SM_BF16><<<512, 256, 0, stream>>>(xn, wt_caq, caqb, nullptr, bufA, MQ, 512, 512);
  hipMemsetAsync(ksum, 0, (size_t)2 * 32 * 64 * 4, stream);
  hipMemsetAsync(ctxb, 0, (size_t)2 * 32 * 64 * 64 * 4, stream);
  for (int br = 0; br < 2; br++) {
    const float* yy  = br ? y1 : y0;
    const float* lg  = br ? ln21g : ln20g;
    const float* lb  = br ? ln21b : ln20b;
    const short* wk  = br ? wt_cak1 : wt_cak0;
    const float* bk  = br ? cak1b : cak0b;
    const short* wv  = br ? wt_cav1 : wt_cav0;
    const float* bv  = br ? cav1b : cav0b;
    ln_kernel<<<MKV, 256, 0, stream>>>(yy, lg, lb, bufD);
    gemm_bt<EPI_B_SM_BF16><<<256, 256, 0, stream>>>(bufD, wk, bk, nullptr, bufB, MKV, 512, 512);
    gemm_bt<EPI_B_BF16><<<256, 256, 0, stream>>>(bufD, wv, bv, nullptr, bufC, MKV, 512, 512);
    colsum_kernel<<<256, 256, 0, stream>>>(bufB, ksum + (size_t)br * 2048, TBD);
    ctx_kernel<<<256, 256, 0, stream>>>(bufB, bufC, ctxb + (size_t)br * 32 * 4096, TBD, 8);
  }
  qctx_kernel<<<32 * (TQD / 128), 256, 0, stream>>>(bufA, ctxb, ksum, bufD, TQD, 2);
  gemm_bt<EPI_B_RES_F32><<<512, 256, 0, stream>>>(bufD, wt_cap, capb, x, xout, MQ, 512, 512);

  // ---- MLP 1 ----
  ln_kernel<<<MQ, 256, 0, stream>>>(xout, ln3g, ln3b, xn);
  gemm_bt<EPI_B_GELU_BF16><<<2048, 256, 0, stream>>>(xn, wt_m1w1, m1b1, nullptr, h1, MQ, 2048, 512);
  gemm_bt<EPI_B_RES_F32><<<512, 256, 0, stream>>>(h1, wt_m1w2, m1b2, xout, xout, MQ, 512, 2048);

  // ---- self-attention ----
  ln_kernel<<<MQ, 256, 0, stream>>>(xout, ln4g, ln4b, xn);
  gemm_bt<EPI_B_SM_BF16><<<512, 256, 0, stream>>>(xn, wt_saq, saqb, nullptr, bufA, MQ, 512, 512);
  gemm_bt<EPI_B_SM_BF16><<<512, 256, 0, stream>>>(xn, wt_sak, sakb, nullptr, bufB, MQ, 512, 512);
  gemm_bt<EPI_B_BF16><<<512, 256, 0, stream>>>(xn, wt_sav, savb, nullptr, bufC, MQ, 512, 512);
  hipMemsetAsync(ksum, 0, (size_t)32 * 64 * 4, stream);
  hipMemsetAsync(ctxb, 0, (size_t)32 * 64 * 64 * 4, stream);
  colsum_kernel<<<256, 256, 0, stream>>>(bufB, ksum, TQD);
  ctx_kernel<<<256, 256, 0, stream>>>(bufB, bufC, ctxb, TQD, 8);
  qctx_kernel<<<32 * (TQD / 128), 256, 0, stream>>>(bufA, ctxb, ksum, bufD, TQD, 1);
  gemm_bt<EPI_B_RES_F32><<<512, 256, 0, stream>>>(bufD, wt_sap, sapb, xout, xout, MQ, 512, 512);

  // ---- MLP 2 ----
  ln_kernel<<<MQ, 256, 0, stream>>>(xout, ln5g, ln5b, xn);
  gemm_bt<EPI_B_GELU_BF16><<<2048, 256, 0, stream>>>(xn, wt_m2w1, m2b1, nullptr, h1, MQ, 2048, 512);
  gemm_bt<EPI_B_RES_F32><<<512, 256, 0, stream>>>(h1, wt_m2w2, m2b2, xout, xout, MQ, 512, 2048);
}

// Round 3
// 753.432 us; speedup vs baseline: 1.2371x; 1.0072x over previous
//
#include <hip/hip_runtime.h>
#include <hip/hip_bf16.h>
#include <math.h>

// Problem constants
#define NBATCH 4
#define TQD 4096
#define TBD 2048
#define CDIM 512
#define NH 8
#define HD 64
#define NINNER 2048

using short8 = __attribute__((ext_vector_type(8))) short;
using f32x4  = __attribute__((ext_vector_type(4))) float;

__device__ __forceinline__ float b2f(short s) {
  return __uint_as_float(((unsigned)(unsigned short)s) << 16);
}
__device__ __forceinline__ short f2b(float f) {
  unsigned u = __float_as_uint(f);
  return (short)((u + 0x7FFFu + ((u >> 16) & 1u)) >> 16);
}
__device__ __forceinline__ unsigned pk2(float a, float b) {
  float2 t; t.x = a; t.y = b;
  __hip_bfloat162 h = __float22bfloat162_rn(t);
  return *(unsigned*)&h;
}
__device__ __forceinline__ float gelu_fast(float x) {
  float x3 = x * x * x;
  float y2 = 1.5957691216f * (x + 0.044715f * x3);   // 2*sqrt(2/pi)*(x+...)
  float e = __expf(y2);
  return x * e / (e + 1.0f);                          // x*sigmoid(y2); inf-safe
}
__device__ __forceinline__ void gload16(const short* g, short* l) {
  __builtin_amdgcn_global_load_lds((const __attribute__((address_space(1))) void*)g,
                                   (__attribute__((address_space(3))) void*)l, 16, 0, 0);
}

// ---------------- LayerNorm (fp32 in -> bf16 out), one block per row, C=512
__launch_bounds__(256)
__global__ void ln_kernel(const float* __restrict__ x, const float* __restrict__ g,
                          const float* __restrict__ b, short* __restrict__ out)
{
  int r = blockIdx.x;
  int tid = threadIdx.x;
  float2 v = ((const float2*)(x + (size_t)r * CDIM))[tid];
  float s = v.x + v.y, s2 = v.x * v.x + v.y * v.y;
#pragma unroll
  for (int m = 1; m < 64; m <<= 1) { s += __shfl_xor(s, m); s2 += __shfl_xor(s2, m); }
  __shared__ float red[8];
  int wave = tid >> 6;
  if ((tid & 63) == 0) { red[wave] = s; red[4 + wave] = s2; }
  __syncthreads();
  s  = red[0] + red[1] + red[2] + red[3];
  s2 = red[4] + red[5] + red[6] + red[7];
  float mean = s * (1.0f / CDIM);
  float var  = s2 * (1.0f / CDIM) - mean * mean;
  float inv  = rsqrtf(var + 1e-5f);
  float2 gg = ((const float2*)g)[tid];
  float2 bb = ((const float2*)b)[tid];
  short2 o;
  o.x = f2b((v.x - mean) * inv * gg.x + bb.x);
  o.y = f2b((v.y - mean) * inv * gg.y + bb.y);
  *((short2*)(out + (size_t)r * CDIM + 2 * tid)) = o;
}

// ---------------- batched transpose+convert: W[K][N] f32 -> Wt[N][K] bf16
struct TcvtDesc {
  const float* src[14];
  short* dst[14];
  int K[14], N[14], nblk[14];
};
__launch_bounds__(256)
__global__ void tcvt_all(TcvtDesc d)
{
  int blk = blockIdx.x, wi = 0;
  while (blk >= d.nblk[wi]) { blk -= d.nblk[wi]; wi++; }
  const float* __restrict__ W = d.src[wi];
  short* __restrict__ Wt = d.dst[wi];
  int K = d.K[wi], N = d.N[wi];
  __shared__ float t[32][33];
  int nbk = K >> 5;
  int bk = blk % nbk, bn = blk / nbk;
  int cx = threadIdx.x & 31, cy = threadIdx.x >> 5;
#pragma unroll
  for (int i = 0; i < 4; i++)
    t[cy + 8 * i][cx] = W[(size_t)(bk * 32 + cy + 8 * i) * N + bn * 32 + cx];
  __syncthreads();
#pragma unroll
  for (int i = 0; i < 4; i++)
    Wt[(size_t)(bn * 32 + cy + 8 * i) * K + bk * 32 + cx] = f2b(t[cx][cy + 8 * i]);
}

// ---------------- main GEMM (m97 structure, swapped-operand C layout):
// C[M][N] = A[M][K]*Bt[N][K]^T + bias. global_load_lds w=16 into LINEAR LDS
// [128][32]; 128x128 tile, BK=32, 4 waves (2x2), 4x4 16x16x32 MFMA frags.
// mfma(bfr, af) => lane holds C[m*16+l15][n*16+g*4+r], r=0..3 consecutive cols
// -> packed uint2 / float4 epilogue stores.
enum { EPI_B_BF16 = 0, EPI_B_GELU_BF16 = 1, EPI_B_RES_F32 = 2, EPI_B_SM_BF16 = 3 };

template<int EPI>
__launch_bounds__(256)
__global__ void gemm_bt(const short* __restrict__ A, const short* __restrict__ Bt,
                        const float* __restrict__ bias, const float* __restrict__ resid,
                        void* __restrict__ outp, int M, int N, int K)
{
  __shared__ short As[128 * 32];
  __shared__ short Bs[128 * 32];
  int tid = threadIdx.x;
  int lane = tid & 63, wave = tid >> 6;
  int l15 = lane & 15, g = lane >> 4;
  int nbn = N >> 7;
  int bm = blockIdx.x / nbn, bn = blockIdx.x % nbn;
  int wr = wave >> 1, wc = wave & 1;
  f32x4 acc[4][4] = {};

  const short* gA0 = A  + (size_t)(bm * 128 + wave * 16 + (lane >> 2)) * K + (lane & 3) * 8;
  const short* gB0 = Bt + (size_t)(bn * 128 + wave * 16 + (lane >> 2)) * K + (lane & 3) * 8;
  const short* gA1 = gA0 + (size_t)64 * K;
  const short* gB1 = gB0 + (size_t)64 * K;
  short* lA0 = As + wave * 512;
  short* lA1 = As + wave * 512 + 2048;
  short* lB0 = Bs + wave * 512;
  short* lB1 = Bs + wave * 512 + 2048;
  const short* ra = As + (wr * 64 + l15) * 32 + g * 8;
  const short* rb = Bs + (wc * 64 + l15) * 32 + g * 8;

  for (int kt = 0; kt < K; kt += 32) {
    __syncthreads();
    gload16(gA0 + kt, lA0);
    gload16(gA1 + kt, lA1);
    gload16(gB0 + kt, lB0);
    gload16(gB1 + kt, lB1);
    __syncthreads();
    short8 af[4], bfr[4];
#pragma unroll
    for (int m = 0; m < 4; m++) af[m]  = *(const short8*)(ra + m * 16 * 32);
#pragma unroll
    for (int n = 0; n < 4; n++) bfr[n] = *(const short8*)(rb + n * 16 * 32);
#pragma unroll
    for (int m = 0; m < 4; m++)
#pragma unroll
      for (int n = 0; n < 4; n++)
        acc[m][n] = __builtin_amdgcn_mfma_f32_16x16x32_bf16(bfr[n], af[m], acc[m][n], 0, 0, 0);
  }

  int row0 = bm * 128 + wr * 64, col0 = bn * 128 + wc * 64;
  // bias: 4 consecutive cols per (n) -> float4
#pragma unroll
  for (int n = 0; n < 4; n++) {
    f32x4 bz = *(const f32x4*)(bias + col0 + n * 16 + g * 4);
#pragma unroll
    for (int m = 0; m < 4; m++)
#pragma unroll
      for (int r = 0; r < 4; r++)
        acc[m][n][r] += bz[r];
  }
  if (EPI == EPI_B_SM_BF16) {
    // softmax over each 64-col head chunk: per m-row, 16 in-lane + lanes {l15,+16,+32,+48}
#pragma unroll
    for (int m = 0; m < 4; m++) {
      float mx = acc[m][0][0];
#pragma unroll
      for (int n = 0; n < 4; n++)
#pragma unroll
        for (int r = 0; r < 4; r++) mx = fmaxf(mx, acc[m][n][r]);
      mx = fmaxf(mx, __shfl_xor(mx, 16));
      mx = fmaxf(mx, __shfl_xor(mx, 32));
      float s = 0.0f;
#pragma unroll
      for (int n = 0; n < 4; n++)
#pragma unroll
        for (int r = 0; r < 4; r++) {
          float e = __expf(acc[m][n][r] - mx);
          acc[m][n][r] = e;
          s += e;
        }
      s += __shfl_xor(s, 16);
      s += __shfl_xor(s, 32);
      float inv = 1.0f / s;
#pragma unroll
      for (int n = 0; n < 4; n++)
#pragma unroll
        for (int r = 0; r < 4; r++) acc[m][n][r] *= inv;
    }
  }
  if (EPI == EPI_B_GELU_BF16) {
#pragma unroll
    for (int m = 0; m < 4; m++)
#pragma unroll
      for (int n = 0; n < 4; n++)
#pragma unroll
        for (int r = 0; r < 4; r++)
          acc[m][n][r] = gelu_fast(acc[m][n][r]);
  }
#pragma unroll
  for (int m = 0; m < 4; m++) {
    int row = row0 + m * 16 + l15;
#pragma unroll
    for (int n = 0; n < 4; n++) {
      size_t base = (size_t)row * N + col0 + n * 16 + g * 4;
      if (EPI == EPI_B_RES_F32) {
        f32x4 rv = *(const f32x4*)(resid + base);
        f32x4 o;
#pragma unroll
        for (int r = 0; r < 4; r++) o[r] = rv[r] + acc[m][n][r];
        *(f32x4*)((float*)outp + base) = o;
      } else {
        uint2 u;
        u.x = pk2(acc[m][n][0], acc[m][n][1]);
        u.y = pk2(acc[m][n][2], acc[m][n][3]);
        *(uint2*)((unsigned short*)outp + base) = u;
      }
    }
  }
}

// ---------------- ctx += k^T v per (b,h); grid = 32*parts, atomics into zeroed ctx
#define LDC 40
__launch_bounds__(256)
__global__ void ctx_kernel(const short* __restrict__ k, const short* __restrict__ v,
                           float* __restrict__ ctx, int T, int parts)
{
  __shared__ short kT[4][64 * LDC];
  __shared__ short vT[4][64 * LDC];
  int bh = blockIdx.x & 31, part = blockIdx.x >> 5;
  int b = bh >> 3, h = bh & 7;
  int tid = threadIdx.x, lane = tid & 63, wave = tid >> 6;
  int l15 = lane & 15, g = lane >> 4;
  int tlen = T / (4 * parts);
  int tbeg = (part * 4 + wave) * tlen;
  f32x4 acc[4][4] = {};
  short* myK = kT[wave];
  short* myV = vT[wave];
  for (int t0 = tbeg; t0 < tbeg + tlen; t0 += 32) {
#pragma unroll
    for (int j = 0; j < 4; j++) {
      int c = lane + j * 64;          // 256 chunks of 8 -> 32x64 tile
      int r = c >> 3, d0 = (c & 7) * 8;
      short8 kv = *(const short8*)(k + (size_t)(b * T + t0 + r) * CDIM + h * 64 + d0);
      short8 vv = *(const short8*)(v + (size_t)(b * T + t0 + r) * CDIM + h * 64 + d0);
#pragma unroll
      for (int i = 0; i < 8; i++) {
        myK[(d0 + i) * LDC + r] = kv[i];
        myV[(d0 + i) * LDC + r] = vv[i];
      }
    }
    __syncthreads();
    short8 af[4], bfr[4];
#pragma unroll
    for (int m = 0; m < 4; m++) af[m]  = *(const short8*)(myK + (m * 16 + l15) * LDC + g * 8);
#pragma unroll
    for (int n = 0; n < 4; n++) bfr[n] = *(const short8*)(myV + (n * 16 + l15) * LDC + g * 8);
#pragma unroll
    for (int m = 0; m < 4; m++)
#pragma unroll
      for (int n = 0; n < 4; n++)
        acc[m][n] = __builtin_amdgcn_mfma_f32_16x16x32_bf16(af[m], bfr[n], acc[m][n], 0, 0, 0);
    __syncthreads();
  }
  float* cp = ctx + (size_t)bh * 64 * 64;
#pragma unroll
  for (int m = 0; m < 4; m++)
#pragma unroll
    for (int n = 0; n < 4; n++)
#pragma unroll
      for (int r = 0; r < 4; r++)
        atomicAdd(cp + (m * 16 + g * 4 + r) * 64 + (n * 16 + l15), acc[m][n][r]);
}

// ---------------- column sums of softmaxed k per (b,h): ksum[bh][64]
__launch_bounds__(256)
__global__ void colsum_kernel(const short* __restrict__ k, float* __restrict__ ksum, int T)
{
  int part = blockIdx.x & 7, bh = blockIdx.x >> 3;
  int b = bh >> 3, h = bh & 7;
  int d = threadIdx.x & 63, tq = threadIdx.x >> 6;
  int tlen = T >> 3, t0 = part * tlen;
  float s = 0.0f;
  for (int t = t0 + tq; t < t0 + tlen; t += 4)
    s += b2f(k[(size_t)(b * T + t) * CDIM + h * 64 + d]);
  atomicAdd(&ksum[bh * 64 + d], s);
}

// ---------------- out[t,:] = q[t,:] + sum_br dinv(t) * (q[t,:] @ ctx[br]);
// d_inv computed in-kernel from ksum.
#define LQ 72
__launch_bounds__(256)
__global__ void qctx_kernel(const short* __restrict__ q,
                            const float* __restrict__ ctx,   // [nb][32][64][64]
                            const float* __restrict__ ksum,  // [nb][32][64]
                            short* __restrict__ outp, int T, int nb)
{
  __shared__ short qs[128 * LQ];
  __shared__ short cT[2][64 * LQ];
  __shared__ float dls[2][128];
  int ntb = T >> 7;
  int bh = blockIdx.x / ntb, tq = blockIdx.x % ntb;
  int b = bh >> 3, h = bh & 7;
  int tid = threadIdx.x, lane = tid & 63, wave = tid >> 6;
  int l15 = lane & 15, g = lane >> 4;
  size_t qbase = (size_t)(b * T + tq * 128) * CDIM + h * 64;

#pragma unroll
  for (int j = 0; j < 4; j++) {
    int c = tid + j * 256;            // 1024 chunks of 8 -> 128x64 tile
    int r = c >> 3, d0 = (c & 7) * 8;
    *(short8*)(qs + r * LQ + d0) = *(const short8*)(q + qbase + (size_t)r * CDIM + d0);
  }
  for (int br = 0; br < nb; br++) {
    const float* cp = ctx + ((size_t)br * 32 + bh) * 4096;
#pragma unroll
    for (int j = 0; j < 16; j++) {
      int e2 = tid + j * 256;
      int dd = e2 >> 6, ee = e2 & 63;
      cT[br][ee * LQ + dd] = f2b(cp[e2]);
    }
  }
  __syncthreads();

  int r0 = wave * 32;
  // fused d_inv: 2 lanes per row, 32 d each
  for (int br = 0; br < nb; br++) {
    int row = r0 + (lane >> 1);
    int dbase = (lane & 1) * 32;
    const float* kp = ksum + ((size_t)br * 32 + bh) * 64 + dbase;
    float s = 0.0f;
#pragma unroll
    for (int d = 0; d < 32; d++)
      s += b2f(qs[row * LQ + dbase + d]) * kp[d];
    s += __shfl_xor(s, 1);
    if (!(lane & 1)) dls[br][row] = 1.0f / fmaxf(s, 1e-9f);
  }

  short8 af[2][2];
#pragma unroll
  for (int m = 0; m < 2; m++)
#pragma unroll
    for (int kk = 0; kk < 2; kk++)
      af[m][kk] = *(const short8*)(qs + (r0 + m * 16 + l15) * LQ + kk * 32 + g * 8);

  float ofin[2][4][4];
#pragma unroll
  for (int m = 0; m < 2; m++)
#pragma unroll
    for (int n = 0; n < 4; n++)
#pragma unroll
      for (int r = 0; r < 4; r++)
        ofin[m][n][r] = b2f(qs[(r0 + m * 16 + g * 4 + r) * LQ + n * 16 + l15]);

  for (int br = 0; br < nb; br++) {
    f32x4 acc[2][4] = {};
#pragma unroll
    for (int kk = 0; kk < 2; kk++) {
      short8 bfr[4];
#pragma unroll
      for (int n = 0; n < 4; n++)
        bfr[n] = *(const short8*)(cT[br] + (n * 16 + l15) * LQ + kk * 32 + g * 8);
#pragma unroll
      for (int m = 0; m < 2; m++)
#pragma unroll
        for (int n = 0; n < 4; n++)
          acc[m][n] = __builtin_amdgcn_mfma_f32_16x16x32_bf16(af[m][kk], bfr[n], acc[m][n], 0, 0, 0);
    }
#pragma unroll
    for (int m = 0; m < 2; m++)
#pragma unroll
      for (int n = 0; n < 4; n++)
#pragma unroll
        for (int r = 0; r < 4; r++)
          ofin[m][n][r] += dls[br][r0 + m * 16 + g * 4 + r] * acc[m][n][r];
  }

#pragma unroll
  for (int m = 0; m < 2; m++)
#pragma unroll
    for (int n = 0; n < 4; n++)
#pragma unroll
      for (int r = 0; r < 4; r++) {
        int row = r0 + m * 16 + g * 4 + r;
        int col = n * 16 + l15;
        outp[qbase + (size_t)row * CDIM + col] = f2b(ofin[m][n][r]);
      }
}

extern "C" void kernel_launch(void* const* d_in, const int* in_sizes, int n_in,
                              void* d_out, int out_size, void* d_ws, size_t ws_size,
                              hipStream_t stream)
{
  (void)in_sizes; (void)n_in; (void)out_size; (void)ws_size;
  const float* x     = (const float*)d_in[0];
  const float* y0    = (const float*)d_in[1];
  const float* y1    = (const float*)d_in[2];
  const float* ln1g  = (const float*)d_in[3];
  const float* ln1b  = (const float*)d_in[4];
  const float* ln20g = (const float*)d_in[5];
  const float* ln20b = (const float*)d_in[6];
  const float* ln21g = (const float*)d_in[7];
  const float* ln21b = (const float*)d_in[8];
  const float* ln3g  = (const float*)d_in[9];
  const float* ln3b  = (const float*)d_in[10];
  const float* ln4g  = (const float*)d_in[11];
  const float* ln4b  = (const float*)d_in[12];
  const float* ln5g  = (const float*)d_in[13];
  const float* ln5b  = (const float*)d_in[14];
  const float* caqw  = (const float*)d_in[15];
  const float* caqb  = (const float*)d_in[16];
  const float* cak0w = (const float*)d_in[17];
  const float* cak0b = (const float*)d_in[18];
  const float* cav0w = (const float*)d_in[19];
  const float* cav0b = (const float*)d_in[20];
  const float* cak1w = (const float*)d_in[21];
  const float* cak1b = (const float*)d_in[22];
  const float* cav1w = (const float*)d_in[23];
  const float* cav1b = (const float*)d_in[24];
  const float* capw  = (const float*)d_in[25];
  const float* capb  = (const float*)d_in[26];
  const float* saqw  = (const float*)d_in[27];
  const float* saqb  = (const float*)d_in[28];
  const float* sakw  = (const float*)d_in[29];
  const float* sakb  = (const float*)d_in[30];
  const float* savw  = (const float*)d_in[31];
  const float* savb  = (const float*)d_in[32];
  const float* sapw  = (const float*)d_in[33];
  const float* sapb  = (const float*)d_in[34];
  const float* m1w1  = (const float*)d_in[35];
  const float* m1b1  = (const float*)d_in[36];
  const float* m1w2  = (const float*)d_in[37];
  const float* m1b2  = (const float*)d_in[38];
  const float* m2w1  = (const float*)d_in[39];
  const float* m2b1  = (const float*)d_in[40];
  const float* m2w2  = (const float*)d_in[41];
  const float* m2b2  = (const float*)d_in[42];
  float* xout = (float*)d_out;

  char* p = (char*)d_ws;
  size_t off = 0;
  auto take = [&](size_t bytes) {
    char* r = p + off;
    off += (bytes + 255) & ~(size_t)255;
    return r;
  };
  const size_t W512 = (size_t)512 * 512 * 2;
  const size_t WMLP = (size_t)2048 * 512 * 2;
  short* wt_caq  = (short*)take(W512);
  short* wt_cak0 = (short*)take(W512);
  short* wt_cav0 = (short*)take(W512);
  short* wt_cak1 = (short*)take(W512);
  short* wt_cav1 = (short*)take(W512);
  short* wt_cap  = (short*)take(W512);
  short* wt_saq  = (short*)take(W512);
  short* wt_sak  = (short*)take(W512);
  short* wt_sav  = (short*)take(W512);
  short* wt_sap  = (short*)take(W512);
  short* wt_m1w1 = (short*)take(WMLP);
  short* wt_m1w2 = (short*)take(WMLP);
  short* wt_m2w1 = (short*)take(WMLP);
  short* wt_m2w2 = (short*)take(WMLP);
  const size_t ACT = (size_t)16384 * 512 * 2;
  short* xn   = (short*)take(ACT);
  short* bufA = (short*)take(ACT);   // q
  short* bufB = (short*)take(ACT);   // k
  short* bufC = (short*)take(ACT);   // v
  short* bufD = (short*)take(ACT);   // yn / attn-out
  short* h1   = (short*)take((size_t)16384 * 2048 * 2);
  float* ksum  = (float*)take((size_t)2 * 32 * 64 * 4);
  float* ctxb  = (float*)take((size_t)2 * 32 * 64 * 64 * 4);

  const int MQ  = NBATCH * TQD;   // 16384
  const int MKV = NBATCH * TBD;   // 8192

  // ---- weight transpose+convert (single batched launch) ----
  {
    TcvtDesc d;
    const float* srcs[14] = {caqw, cak0w, cav0w, cak1w, cav1w, capw,
                             saqw, sakw, savw, sapw, m1w1, m1w2, m2w1, m2w2};
    short* dsts[14] = {wt_caq, wt_cak0, wt_cav0, wt_cak1, wt_cav1, wt_cap,
                       wt_saq, wt_sak, wt_sav, wt_sap, wt_m1w1, wt_m1w2, wt_m2w1, wt_m2w2};
    int Ks[14] = {512,512,512,512,512,512,512,512,512,512, 512,2048,512,2048};
    int Ns[14] = {512,512,512,512,512,512,512,512,512,512, 2048,512,2048,512};
    int total = 0;
    for (int i = 0; i < 14; i++) {
      d.src[i] = srcs[i]; d.dst[i] = dsts[i]; d.K[i] = Ks[i]; d.N[i] = Ns[i];
      d.nblk[i] = (Ks[i] >> 5) * (Ns[i] >> 5);
      total += d.nblk[i];
    }
    tcvt_all<<<total, 256, 0, stream>>>(d);
  }

  // ---- cross-attention ----
  ln_kernel<<<MQ, 256, 0, stream>>>(x, ln1g, ln1b, xn);
  gemm_bt<EPI_B_SM_BF16><<<512, 256, 0, stream>>>(xn, wt_caq, caqb, nullptr, bufA, MQ, 512, 512);
  hipMemsetAsync(ksum, 0, (size_t)2 * 32 * 64 * 4, stream);
  hipMemsetAsync(ctxb, 0, (size_t)2 * 32 * 64 * 64 * 4, stream);
  for (int br = 0; br < 2; br++) {
    const float* yy  = br ? y1 : y0;
    const float* lg  = br ? ln21g : ln20g;
    const float* lb  = br ? ln21b : ln20b;
    const short* wk  = br ? wt_cak1 : wt_cak0;
    const float* bk  = br ? cak1b : cak0b;
    const short* wv  = br ? wt_cav1 : wt_cav0;
    const float* bv  = br ? cav1b : cav0b;
    ln_kernel<<<MKV, 256, 0, stream>>>(yy, lg, lb, bufD);
    gemm_bt<EPI_B_SM_BF16><<<256, 256, 0, stream>>>(bufD, wk, bk, nullptr, bufB, MKV, 512, 512);
    gemm_bt<EPI_B_BF16><<<256, 256, 0, stream>>>(bufD, wv, bv, nullptr, bufC, MKV, 512, 512);
    colsum_kernel<<<256, 256, 0, stream>>>(bufB, ksum + (size_t)br * 2048, TBD);
    ctx_kernel<<<256, 256, 0, stream>>>(bufB, bufC, ctxb + (size_t)br * 32 * 4096, TBD, 8);
  }
  qctx_kernel<<<32 * (TQD / 128), 256, 0, stream>>>(bufA, ctxb, ksum, bufD, TQD, 2);
  gemm_bt<EPI_B_RES_F32><<<512, 256, 0, stream>>>(bufD, wt_cap, capb, x, xout, MQ, 512, 512);

  // ---- MLP 1 ----
  ln_kernel<<<MQ, 256, 0, stream>>>(xout, ln3g, ln3b, xn);
  gemm_bt<EPI_B_GELU_BF16><<<2048, 256, 0, stream>>>(xn, wt_m1w1, m1b1, nullptr, h1, MQ, 2048, 512);
  gemm_bt<EPI_B_RES_F32><<<512, 256, 0, stream>>>(h1, wt_m1w2, m1b2, xout, xout, MQ, 512, 2048);

  // ---- self-attention ----
  ln_kernel<<<MQ, 256, 0, stream>>>(xout, ln4g, ln4b, xn);
  gemm_bt<EPI_B_SM_BF16><<<512, 256, 0, stream>>>(xn, wt_saq, saqb, nullptr, bufA, MQ, 512, 512);
  gemm_bt<EPI_B_SM_BF16><<<512, 256, 0, stream>>>(xn, wt_sak, sakb, nullptr, bufB, MQ, 512, 512);
  gemm_bt<EPI_B_BF16><<<512, 256, 0, stream>>>(xn, wt_sav, savb, nullptr, bufC, MQ, 512, 512);
  hipMemsetAsync(ksum, 0, (size_t)32 * 64 * 4, stream);
  hipMemsetAsync(ctxb, 0, (size_t)32 * 64 * 64 * 4, stream);
  colsum_kernel<<<256, 256, 0, stream>>>(bufB, ksum, TQD);
  ctx_kernel<<<256, 256, 0, stream>>>(bufB, bufC, ctxb, TQD, 8);
  qctx_kernel<<<32 * (TQD / 128), 256, 0, stream>>>(bufA, ctxb, ksum, bufD, TQD, 1);
  gemm_bt<EPI_B_RES_F32><<<512, 256, 0, stream>>>(bufD, wt_sap, sapb, xout, xout, MQ, 512, 512);

  // ---- MLP 2 ----
  ln_kernel<<<MQ, 256, 0, stream>>>(xout, ln5g, ln5b, xn);
  gemm_bt<EPI_B_GELU_BF16><<<2048, 256, 0, stream>>>(xn, wt_m2w1, m2b1, nullptr, h1, MQ, 2048, 512);
  gemm_bt<EPI_B_RES_F32><<<512, 256, 0, stream>>>(h1, wt_m2w2, m2b2, xout, xout, MQ, 512, 2048);
}

// Round 4
// 701.366 us; speedup vs baseline: 1.3289x; 1.0742x over previous
//
#include <hip/hip_runtime.h>
#include <hip/hip_bf16.h>
#include <math.h>

// Problem constants
#define NBATCH 4
#define TQD 4096
#define TBD 2048
#define CDIM 512
#define NH 8
#define HD 64
#define NINNER 2048

using short8 = __attribute__((ext_vector_type(8))) short;
using f32x4  = __attribute__((ext_vector_type(4))) float;

__device__ __forceinline__ float b2f(short s) {
  return __uint_as_float(((unsigned)(unsigned short)s) << 16);
}
__device__ __forceinline__ short f2b(float f) {
  unsigned u = __float_as_uint(f);
  return (short)((u + 0x7FFFu + ((u >> 16) & 1u)) >> 16);
}
__device__ __forceinline__ unsigned pk2(float a, float b) {
  float2 t; t.x = a; t.y = b;
  __hip_bfloat162 h = __float22bfloat162_rn(t);
  return *(unsigned*)&h;
}
__device__ __forceinline__ float gelu_fast(float x) {
  float x3 = x * x * x;
  float y2 = 1.5957691216f * (x + 0.044715f * x3);   // 2*sqrt(2/pi)*(x+...)
  float e = __expf(y2);
  return x * e / (e + 1.0f);                          // x*sigmoid(y2); inf-safe
}
__device__ __forceinline__ void gload16(const short* g, short* l) {
  __builtin_amdgcn_global_load_lds((const __attribute__((address_space(1))) void*)g,
                                   (__attribute__((address_space(3))) void*)l, 16, 0, 0);
}

// ---------------- LayerNorm (fp32 in -> bf16 out), one block per row, C=512
__launch_bounds__(256)
__global__ void ln_kernel(const float* __restrict__ x, const float* __restrict__ g,
                          const float* __restrict__ b, short* __restrict__ out)
{
  int r = blockIdx.x;
  int tid = threadIdx.x;
  float2 v = ((const float2*)(x + (size_t)r * CDIM))[tid];
  float s = v.x + v.y, s2 = v.x * v.x + v.y * v.y;
#pragma unroll
  for (int m = 1; m < 64; m <<= 1) { s += __shfl_xor(s, m); s2 += __shfl_xor(s2, m); }
  __shared__ float red[8];
  int wave = tid >> 6;
  if ((tid & 63) == 0) { red[wave] = s; red[4 + wave] = s2; }
  __syncthreads();
  s  = red[0] + red[1] + red[2] + red[3];
  s2 = red[4] + red[5] + red[6] + red[7];
  float mean = s * (1.0f / CDIM);
  float var  = s2 * (1.0f / CDIM) - mean * mean;
  float inv  = rsqrtf(var + 1e-5f);
  float2 gg = ((const float2*)g)[tid];
  float2 bb = ((const float2*)b)[tid];
  short2 o;
  o.x = f2b((v.x - mean) * inv * gg.x + bb.x);
  o.y = f2b((v.y - mean) * inv * gg.y + bb.y);
  *((short2*)(out + (size_t)r * CDIM + 2 * tid)) = o;
}

// ---------------- batched transpose+convert: W[K][N] f32 -> Wt[N][K] bf16
struct TcvtDesc {
  const float* src[14];
  short* dst[14];
  int K[14], N[14], nblk[14];
};
__launch_bounds__(256)
__global__ void tcvt_all(TcvtDesc d)
{
  int blk = blockIdx.x, wi = 0;
  while (blk >= d.nblk[wi]) { blk -= d.nblk[wi]; wi++; }
  const float* __restrict__ W = d.src[wi];
  short* __restrict__ Wt = d.dst[wi];
  int K = d.K[wi], N = d.N[wi];
  __shared__ float t[32][33];
  int nbk = K >> 5;
  int bk = blk % nbk, bn = blk / nbk;
  int cx = threadIdx.x & 31, cy = threadIdx.x >> 5;
#pragma unroll
  for (int i = 0; i < 4; i++)
    t[cy + 8 * i][cx] = W[(size_t)(bk * 32 + cy + 8 * i) * N + bn * 32 + cx];
  __syncthreads();
#pragma unroll
  for (int i = 0; i < 4; i++)
    Wt[(size_t)(bn * 32 + cy + 8 * i) * K + bk * 32 + cx] = f2b(t[cx][cy + 8 * i]);
}

// ---------------- main GEMM: C[M][N] = A[M][K]*Bt[N][K]^T + bias (+epilogue)
// 128x128 tile, BK=32, double-buffered LDS with counted vmcnt (T3/T4 minimum):
//   STAGE(nxt) -> vmcnt(4) -> s_barrier -> ds_read(cur)+MFMA -> s_barrier
// so next tile's global_load_lds stay in flight across the compute phase.
// LDS bank swizzle (rule #21): linear gload_lds dest + inverse-swizzled global
// source + swizzled ds_read: slot' = slot ^ ((row>>1)&3)  -> 2-way (free).
// Swapped-operand MFMA: lane holds C[m*16+l15][n*16+g*4+r] -> packed stores.
enum { EPI_B_BF16 = 0, EPI_B_GELU_BF16 = 1, EPI_B_RES_F32 = 2, EPI_B_SM_BF16 = 3 };

template<int EPI>
__launch_bounds__(256)
__global__ void gemm_bt(const short* __restrict__ A, const short* __restrict__ Bt,
                        const float* __restrict__ bias, const float* __restrict__ resid,
                        void* __restrict__ outp, int M, int N, int K)
{
  __shared__ short As[2 * 4096];
  __shared__ short Bs[2 * 4096];
  int tid = threadIdx.x;
  int lane = tid & 63, wave = tid >> 6;
  int l15 = lane & 15, g = lane >> 4;
  int nbn = N >> 7;
  // XCD-aware remap (grid always %8==0 here -> bijective)
  int per = gridDim.x >> 3;
  int wg = (blockIdx.x & 7) * per + (blockIdx.x >> 3);
  int bm = wg / nbn, bn = wg % nbn;
  int wr = wave >> 1, wc = wave & 1;
  f32x4 acc[4][4] = {};

  // staging addresses: lane i covers (row = w*16 + i/4, slot = i&3) of the
  // linear LDS chunk; source slot inverse-swizzled so swizzled reads see
  // the right data:  src_slot = (i&3) ^ ((i>>3)&3)   [= (i&3)^((row>>1)&3)]
  int srcslot = (lane & 3) ^ ((lane >> 3) & 3);
  const short* gA0 = A  + (size_t)(bm * 128 + wave * 16 + (lane >> 2)) * K + srcslot * 8;
  const short* gB0 = Bt + (size_t)(bn * 128 + wave * 16 + (lane >> 2)) * K + srcslot * 8;
  const short* gA1 = gA0 + (size_t)64 * K;
  const short* gB1 = gB0 + (size_t)64 * K;
  short* lA0 = As + wave * 512;
  short* lA1 = As + wave * 512 + 2048;
  short* lB0 = Bs + wave * 512;
  short* lB1 = Bs + wave * 512 + 2048;
  // read: fragment (row = wr*64 + m*16 + l15, col-slot g) lives at
  // slot g ^ ((l15>>1)&3)  (row>>1 bits from m,wr vanish mod 4)
  int rslot = (g ^ ((l15 >> 1) & 3)) * 8;
  const short* ra = As + (wr * 64 + l15) * 32 + rslot;
  const short* rb = Bs + (wc * 64 + l15) * 32 + rslot;

  // prologue: stage k-tile 0 into buf 0  (4 loads in flight)
  gload16(gA0, lA0);
  gload16(gA1, lA1);
  gload16(gB0, lB0);
  gload16(gB1, lB1);

  int cur = 0;
  for (int kt = 0; kt < K; kt += 32) {
    if (kt + 32 < K) {
      int nb_ = cur ^ 1;
      gload16(gA0 + kt + 32, lA0 + nb_ * 4096);
      gload16(gA1 + kt + 32, lA1 + nb_ * 4096);
      gload16(gB0 + kt + 32, lB0 + nb_ * 4096);
      gload16(gB1 + kt + 32, lB1 + nb_ * 4096);
      asm volatile("s_waitcnt vmcnt(4)" ::: "memory");   // cur landed; nxt in flight
    } else {
      asm volatile("s_waitcnt vmcnt(0)" ::: "memory");
    }
    __builtin_amdgcn_s_barrier();          // publish cur
    __builtin_amdgcn_sched_barrier(0);
    const short* rac = ra + cur * 4096;
    const short* rbc = rb + cur * 4096;
    short8 af[4], bfr[4];
#pragma unroll
    for (int m = 0; m < 4; m++) af[m]  = *(const short8*)(rac + m * 512);
#pragma unroll
    for (int n = 0; n < 4; n++) bfr[n] = *(const short8*)(rbc + n * 512);
#pragma unroll
    for (int m = 0; m < 4; m++)
#pragma unroll
      for (int n = 0; n < 4; n++)
        acc[m][n] = __builtin_amdgcn_mfma_f32_16x16x32_bf16(bfr[n], af[m], acc[m][n], 0, 0, 0);
    __builtin_amdgcn_sched_barrier(0);
    __builtin_amdgcn_s_barrier();          // reads of cur done -> overwritable
    cur ^= 1;
  }

  int row0 = bm * 128 + wr * 64, col0 = bn * 128 + wc * 64;
  // bias: 4 consecutive cols per (n) -> float4
#pragma unroll
  for (int n = 0; n < 4; n++) {
    f32x4 bz = *(const f32x4*)(bias + col0 + n * 16 + g * 4);
#pragma unroll
    for (int m = 0; m < 4; m++)
#pragma unroll
      for (int r = 0; r < 4; r++)
        acc[m][n][r] += bz[r];
  }
  if (EPI == EPI_B_SM_BF16) {
    // softmax over each 64-col head chunk: per m-row, 16 in-lane + lanes {l15,+16,+32,+48}
#pragma unroll
    for (int m = 0; m < 4; m++) {
      float mx = acc[m][0][0];
#pragma unroll
      for (int n = 0; n < 4; n++)
#pragma unroll
        for (int r = 0; r < 4; r++) mx = fmaxf(mx, acc[m][n][r]);
      mx = fmaxf(mx, __shfl_xor(mx, 16));
      mx = fmaxf(mx, __shfl_xor(mx, 32));
      float s = 0.0f;
#pragma unroll
      for (int n = 0; n < 4; n++)
#pragma unroll
        for (int r = 0; r < 4; r++) {
          float e = __expf(acc[m][n][r] - mx);
          acc[m][n][r] = e;
          s += e;
        }
      s += __shfl_xor(s, 16);
      s += __shfl_xor(s, 32);
      float inv = 1.0f / s;
#pragma unroll
      for (int n = 0; n < 4; n++)
#pragma unroll
        for (int r = 0; r < 4; r++) acc[m][n][r] *= inv;
    }
  }
  if (EPI == EPI_B_GELU_BF16) {
#pragma unroll
    for (int m = 0; m < 4; m++)
#pragma unroll
      for (int n = 0; n < 4; n++)
#pragma unroll
        for (int r = 0; r < 4; r++)
          acc[m][n][r] = gelu_fast(acc[m][n][r]);
  }
#pragma unroll
  for (int m = 0; m < 4; m++) {
    int row = row0 + m * 16 + l15;
#pragma unroll
    for (int n = 0; n < 4; n++) {
      size_t base = (size_t)row * N + col0 + n * 16 + g * 4;
      if (EPI == EPI_B_RES_F32) {
        f32x4 rv = *(const f32x4*)(resid + base);
        f32x4 o;
#pragma unroll
        for (int r = 0; r < 4; r++) o[r] = rv[r] + acc[m][n][r];
        *(f32x4*)((float*)outp + base) = o;
      } else {
        uint2 u;
        u.x = pk2(acc[m][n][0], acc[m][n][1]);
        u.y = pk2(acc[m][n][2], acc[m][n][3]);
        *(uint2*)((unsigned short*)outp + base) = u;
      }
    }
  }
}

// ---------------- ctx += k^T v per (b,h); grid = 32*parts, atomics into zeroed ctx
#define LDC 40
__launch_bounds__(256)
__global__ void ctx_kernel(const short* __restrict__ k, const short* __restrict__ v,
                           float* __restrict__ ctx, int T, int parts)
{
  __shared__ short kT[4][64 * LDC];
  __shared__ short vT[4][64 * LDC];
  int bh = blockIdx.x & 31, part = blockIdx.x >> 5;
  int b = bh >> 3, h = bh & 7;
  int tid = threadIdx.x, lane = tid & 63, wave = tid >> 6;
  int l15 = lane & 15, g = lane >> 4;
  int tlen = T / (4 * parts);
  int tbeg = (part * 4 + wave) * tlen;
  f32x4 acc[4][4] = {};
  short* myK = kT[wave];
  short* myV = vT[wave];
  for (int t0 = tbeg; t0 < tbeg + tlen; t0 += 32) {
#pragma unroll
    for (int j = 0; j < 4; j++) {
      int c = lane + j * 64;          // 256 chunks of 8 -> 32x64 tile
      int r = c >> 3, d0 = (c & 7) * 8;
      short8 kv = *(const short8*)(k + (size_t)(b * T + t0 + r) * CDIM + h * 64 + d0);
      short8 vv = *(const short8*)(v + (size_t)(b * T + t0 + r) * CDIM + h * 64 + d0);
#pragma unroll
      for (int i = 0; i < 8; i++) {
        myK[(d0 + i) * LDC + r] = kv[i];
        myV[(d0 + i) * LDC + r] = vv[i];
      }
    }
    __syncthreads();
    short8 af[4], bfr[4];
#pragma unroll
    for (int m = 0; m < 4; m++) af[m]  = *(const short8*)(myK + (m * 16 + l15) * LDC + g * 8);
#pragma unroll
    for (int n = 0; n < 4; n++) bfr[n] = *(const short8*)(myV + (n * 16 + l15) * LDC + g * 8);
#pragma unroll
    for (int m = 0; m < 4; m++)
#pragma unroll
      for (int n = 0; n < 4; n++)
        acc[m][n] = __builtin_amdgcn_mfma_f32_16x16x32_bf16(af[m], bfr[n], acc[m][n], 0, 0, 0);
    __syncthreads();
  }
  float* cp = ctx + (size_t)bh * 64 * 64;
#pragma unroll
  for (int m = 0; m < 4; m++)
#pragma unroll
    for (int n = 0; n < 4; n++)
#pragma unroll
      for (int r = 0; r < 4; r++)
        atomicAdd(cp + (m * 16 + g * 4 + r) * 64 + (n * 16 + l15), acc[m][n][r]);
}

// ---------------- column sums of softmaxed k per (b,h): ksum[bh][64]
__launch_bounds__(256)
__global__ void colsum_kernel(const short* __restrict__ k, float* __restrict__ ksum, int T)
{
  int part = blockIdx.x & 7, bh = blockIdx.x >> 3;
  int b = bh >> 3, h = bh & 7;
  int d = threadIdx.x & 63, tq = threadIdx.x >> 6;
  int tlen = T >> 3, t0 = part * tlen;
  float s = 0.0f;
  for (int t = t0 + tq; t < t0 + tlen; t += 4)
    s += b2f(k[(size_t)(b * T + t) * CDIM + h * 64 + d]);
  atomicAdd(&ksum[bh * 64 + d], s);
}

// ---------------- out[t,:] = q[t,:] + sum_br dinv(t) * (q[t,:] @ ctx[br]);
// d_inv computed in-kernel from ksum.
#define LQ 72
__launch_bounds__(256)
__global__ void qctx_kernel(const short* __restrict__ q,
                            const float* __restrict__ ctx,   // [nb][32][64][64]
                            const float* __restrict__ ksum,  // [nb][32][64]
                            short* __restrict__ outp, int T, int nb)
{
  __shared__ short qs[128 * LQ];
  __shared__ short cT[2][64 * LQ];
  __shared__ float dls[2][128];
  int ntb = T >> 7;
  int bh = blockIdx.x / ntb, tq = blockIdx.x % ntb;
  int b = bh >> 3, h = bh & 7;
  int tid = threadIdx.x, lane = tid & 63, wave = tid >> 6;
  int l15 = lane & 15, g = lane >> 4;
  size_t qbase = (size_t)(b * T + tq * 128) * CDIM + h * 64;

#pragma unroll
  for (int j = 0; j < 4; j++) {
    int c = tid + j * 256;            // 1024 chunks of 8 -> 128x64 tile
    int r = c >> 3, d0 = (c & 7) * 8;
    *(short8*)(qs + r * LQ + d0) = *(const short8*)(q + qbase + (size_t)r * CDIM + d0);
  }
  for (int br = 0; br < nb; br++) {
    const float* cp = ctx + ((size_t)br * 32 + bh) * 4096;
#pragma unroll
    for (int j = 0; j < 16; j++) {
      int e2 = tid + j * 256;
      int dd = e2 >> 6, ee = e2 & 63;
      cT[br][ee * LQ + dd] = f2b(cp[e2]);
    }
  }
  __syncthreads();

  int r0 = wave * 32;
  // fused d_inv: 2 lanes per row, 32 d each
  for (int br = 0; br < nb; br++) {
    int row = r0 + (lane >> 1);
    int dbase = (lane & 1) * 32;
    const float* kp = ksum + ((size_t)br * 32 + bh) * 64 + dbase;
    float s = 0.0f;
#pragma unroll
    for (int d = 0; d < 32; d++)
      s += b2f(qs[row * LQ + dbase + d]) * kp[d];
    s += __shfl_xor(s, 1);
    if (!(lane & 1)) dls[br][row] = 1.0f / fmaxf(s, 1e-9f);
  }

  short8 af[2][2];
#pragma unroll
  for (int m = 0; m < 2; m++)
#pragma unroll
    for (int kk = 0; kk < 2; kk++)
      af[m][kk] = *(const short8*)(qs + (r0 + m * 16 + l15) * LQ + kk * 32 + g * 8);

  float ofin[2][4][4];
#pragma unroll
  for (int m = 0; m < 2; m++)
#pragma unroll
    for (int n = 0; n < 4; n++)
#pragma unroll
      for (int r = 0; r < 4; r++)
        ofin[m][n][r] = b2f(qs[(r0 + m * 16 + g * 4 + r) * LQ + n * 16 + l15]);

  for (int br = 0; br < nb; br++) {
    f32x4 acc[2][4] = {};
#pragma unroll
    for (int kk = 0; kk < 2; kk++) {
      short8 bfr[4];
#pragma unroll
      for (int n = 0; n < 4; n++)
        bfr[n] = *(const short8*)(cT[br] + (n * 16 + l15) * LQ + kk * 32 + g * 8);
#pragma unroll
      for (int m = 0; m < 2; m++)
#pragma unroll
        for (int n = 0; n < 4; n++)
          acc[m][n] = __builtin_amdgcn_mfma_f32_16x16x32_bf16(af[m][kk], bfr[n], acc[m][n], 0, 0, 0);
    }
#pragma unroll
    for (int m = 0; m < 2; m++)
#pragma unroll
      for (int n = 0; n < 4; n++)
#pragma unroll
        for (int r = 0; r < 4; r++)
          ofin[m][n][r] += dls[br][r0 + m * 16 + g * 4 + r] * acc[m][n][r];
  }

#pragma unroll
  for (int m = 0; m < 2; m++)
#pragma unroll
    for (int n = 0; n < 4; n++)
#pragma unroll
      for (int r = 0; r < 4; r++) {
        int row = r0 + m * 16 + g * 4 + r;
        int col = n * 16 + l15;
        outp[qbase + (size_t)row * CDIM + col] = f2b(ofin[m][n][r]);
      }
}

extern "C" void kernel_launch(void* const* d_in, const int* in_sizes, int n_in,
                              void* d_out, int out_size, void* d_ws, size_t ws_size,
                              hipStream_t stream)
{
  (void)in_sizes; (void)n_in; (void)out_size; (void)ws_size;
  const float* x     = (const float*)d_in[0];
  const float* y0    = (const float*)d_in[1];
  const float* y1    = (const float*)d_in[2];
  const float* ln1g  = (const float*)d_in[3];
  const float* ln1b  = (const float*)d_in[4];
  const float* ln20g = (const float*)d_in[5];
  const float* ln20b = (const float*)d_in[6];
  const float* ln21g = (const float*)d_in[7];
  const float* ln21b = (const float*)d_in[8];
  const float* ln3g  = (const float*)d_in[9];
  const float* ln3b  = (const float*)d_in[10];
  const float* ln4g  = (const float*)d_in[11];
  const float* ln4b  = (const float*)d_in[12];
  const float* ln5g  = (const float*)d_in[13];
  const float* ln5b  = (const float*)d_in[14];
  const float* caqw  = (const float*)d_in[15];
  const float* caqb  = (const float*)d_in[16];
  const float* cak0w = (const float*)d_in[17];
  const float* cak0b = (const float*)d_in[18];
  const float* cav0w = (const float*)d_in[19];
  const float* cav0b = (const float*)d_in[20];
  const float* cak1w = (const float*)d_in[21];
  const float* cak1b = (const float*)d_in[22];
  const float* cav1w = (const float*)d_in[23];
  const float* cav1b = (const float*)d_in[24];
  const float* capw  = (const float*)d_in[25];
  const float* capb  = (const float*)d_in[26];
  const float* saqw  = (const float*)d_in[27];
  const float* saqb  = (const float*)d_in[28];
  const float* sakw  = (const float*)d_in[29];
  const float* sakb  = (const float*)d_in[30];
  const float* savw  = (const float*)d_in[31];
  const float* savb  = (const float*)d_in[32];
  const float* sapw  = (const float*)d_in[33];
  const float* sapb  = (const float*)d_in[34];
  const float* m1w1  = (const float*)d_in[35];
  const float* m1b1  = (const float*)d_in[36];
  const float* m1w2  = (const float*)d_in[37];
  const float* m1b2  = (const float*)d_in[38];
  const float* m2w1  = (const float*)d_in[39];
  const float* m2b1  = (const float*)d_in[40];
  const float* m2w2  = (const float*)d_in[41];
  const float* m2b2  = (const float*)d_in[42];
  float* xout = (float*)d_out;

  char* p = (char*)d_ws;
  size_t off = 0;
  auto take = [&](size_t bytes) {
    char* r = p + off;
    off += (bytes + 255) & ~(size_t)255;
    return r;
  };
  const size_t W512 = (size_t)512 * 512 * 2;
  const size_t WMLP = (size_t)2048 * 512 * 2;
  short* wt_caq  = (short*)take(W512);
  short* wt_cak0 = (short*)take(W512);
  short* wt_cav0 = (short*)take(W512);
  short* wt_cak1 = (short*)take(W512);
  short* wt_cav1 = (short*)take(W512);
  short* wt_cap  = (short*)take(W512);
  short* wt_saq  = (short*)take(W512);
  short* wt_sak  = (short*)take(W512);
  short* wt_sav  = (short*)take(W512);
  short* wt_sap  = (short*)take(W512);
  short* wt_m1w1 = (short*)take(WMLP);
  short* wt_m1w2 = (short*)take(WMLP);
  short* wt_m2w1 = (short*)take(WMLP);
  short* wt_m2w2 = (short*)take(WMLP);
  const size_t ACT = (size_t)16384 * 512 * 2;
  short* xn   = (short*)take(ACT);
  short* bufA = (short*)take(ACT);   // q
  short* bufB = (short*)take(ACT);   // k
  short* bufC = (short*)take(ACT);   // v
  short* bufD = (short*)take(ACT);   // yn / attn-out
  short* h1   = (short*)take((size_t)16384 * 2048 * 2);
  float* ksum  = (float*)take((size_t)2 * 32 * 64 * 4);
  float* ctxb  = (float*)take((size_t)2 * 32 * 64 * 64 * 4);

  const int MQ  = NBATCH * TQD;   // 16384
  const int MKV = NBATCH * TBD;   // 8192

  // ---- weight transpose+convert (single batched launch) ----
  {
    TcvtDesc d;
    const float* srcs[14] = {caqw, cak0w, cav0w, cak1w, cav1w, capw,
                             saqw, sakw, savw, sapw, m1w1, m1w2, m2w1, m2w2};
    short* dsts[14] = {wt_caq, wt_cak0, wt_cav0, wt_cak1, wt_cav1, wt_cap,
                       wt_saq, wt_sak, wt_sav, wt_sap, wt_m1w1, wt_m1w2, wt_m2w1, wt_m2w2};
    int Ks[14] = {512,512,512,512,512,512,512,512,512,512, 512,2048,512,2048};
    int Ns[14] = {512,512,512,512,512,512,512,512,512,512, 2048,512,2048,512};
    int total = 0;
    for (int i = 0; i < 14; i++) {
      d.src[i] = srcs[i]; d.dst[i] = dsts[i]; d.K[i] = Ks[i]; d.N[i] = Ns[i];
      d.nblk[i] = (Ks[i] >> 5) * (Ns[i] >> 5);
      total += d.nblk[i];
    }
    tcvt_all<<<total, 256, 0, stream>>>(d);
  }

  // ---- cross-attention ----
  ln_kernel<<<MQ, 256, 0, stream>>>(x, ln1g, ln1b, xn);
  gemm_bt<EPI_B_SM_BF16><<<512, 256, 0, stream>>>(xn, wt_caq, caqb, nullptr, bufA, MQ, 512, 512);
  hipMemsetAsync(ksum, 0, (size_t)2 * 32 * 64 * 4, stream);
  hipMemsetAsync(ctxb, 0, (size_t)2 * 32 * 64 * 64 * 4, stream);
  for (int br = 0; br < 2; br++) {
    const float* yy  = br ? y1 : y0;
    const float* lg  = br ? ln21g : ln20g;
    const float* lb  = br ? ln21b : ln20b;
    const short* wk  = br ? wt_cak1 : wt_cak0;
    const float* bk  = br ? cak1b : cak0b;
    const short* wv  = br ? wt_cav1 : wt_cav0;
    const float* bv  = br ? cav1b : cav0b;
    ln_kernel<<<MKV, 256, 0, stream>>>(yy, lg, lb, bufD);
    gemm_bt<EPI_B_SM_BF16><<<256, 256, 0, stream>>>(bufD, wk, bk, nullptr, bufB, MKV, 512, 512);
    gemm_bt<EPI_B_BF16><<<256, 256, 0, stream>>>(bufD, wv, bv, nullptr, bufC, MKV, 512, 512);
    colsum_kernel<<<256, 256, 0, stream>>>(bufB, ksum + (size_t)br * 2048, TBD);
    ctx_kernel<<<256, 256, 0, stream>>>(bufB, bufC, ctxb + (size_t)br * 32 * 4096, TBD, 8);
  }
  qctx_kernel<<<32 * (TQD / 128), 256, 0, stream>>>(bufA, ctxb, ksum, bufD, TQD, 2);
  gemm_bt<EPI_B_RES_F32><<<512, 256, 0, stream>>>(bufD, wt_cap, capb, x, xout, MQ, 512, 512);

  // ---- MLP 1 ----
  ln_kernel<<<MQ, 256, 0, stream>>>(xout, ln3g, ln3b, xn);
  gemm_bt<EPI_B_GELU_BF16><<<2048, 256, 0, stream>>>(xn, wt_m1w1, m1b1, nullptr, h1, MQ, 2048, 512);
  gemm_bt<EPI_B_RES_F32><<<512, 256, 0, stream>>>(h1, wt_m1w2, m1b2, xout, xout, MQ, 512, 2048);

  // ---- self-attention ----
  ln_kernel<<<MQ, 256, 0, stream>>>(xout, ln4g, ln4b, xn);
  gemm_bt<EPI_B_SM_BF16><<<512, 256, 0, stream>>>(xn, wt_saq, saqb, nullptr, bufA, MQ, 512, 512);
  gemm_bt<EPI_B_SM_BF16><<<512, 256, 0, stream>>>(xn, wt_sak, sakb, nullptr, bufB, MQ, 512, 512);
  gemm_bt<EPI_B_BF16><<<512, 256, 0, stream>>>(xn, wt_sav, savb, nullptr, bufC, MQ, 512, 512);
  hipMemsetAsync(ksum, 0, (size_t)32 * 64 * 4, stream);
  hipMemsetAsync(ctxb, 0, (size_t)32 * 64 * 64 * 4, stream);
  colsum_kernel<<<256, 256, 0, stream>>>(bufB, ksum, TQD);
  ctx_kernel<<<256, 256, 0, stream>>>(bufB, bufC, ctxb, TQD, 8);
  qctx_kernel<<<32 * (TQD / 128), 256, 0, stream>>>(bufA, ctxb, ksum, bufD, TQD, 1);
  gemm_bt<EPI_B_RES_F32><<<512, 256, 0, stream>>>(bufD, wt_sap, sapb, xout, xout, MQ, 512, 512);

  // ---- MLP 2 ----
  ln_kernel<<<MQ, 256, 0, stream>>>(xout, ln5g, ln5b, xn);
  gemm_bt<EPI_B_GELU_BF16><<<2048, 256, 0, stream>>>(xn, wt_m2w1, m2b1, nullptr, h1, MQ, 2048, 512);
  gemm_bt<EPI_B_RES_F32><<<512, 256, 0, stream>>>(h1, wt_m2w2, m2b2, xout, xout, MQ, 512, 2048);
}

// Round 5
// 656.044 us; speedup vs baseline: 1.4208x; 1.0691x over previous
//
#include <hip/hip_runtime.h>
#include <hip/hip_bf16.h>
#include <math.h>

// Problem constants
#define NBATCH 4
#define TQD 4096
#define TBD 2048
#define CDIM 512
#define NH 8
#define HD 64
#define NINNER 2048

using short8 = __attribute__((ext_vector_type(8))) short;
using f32x4  = __attribute__((ext_vector_type(4))) float;

__device__ __forceinline__ float b2f(short s) {
  return __uint_as_float(((unsigned)(unsigned short)s) << 16);
}
__device__ __forceinline__ short f2b(float f) {
  unsigned u = __float_as_uint(f);
  return (short)((u + 0x7FFFu + ((u >> 16) & 1u)) >> 16);
}
__device__ __forceinline__ unsigned pk2(float a, float b) {
  float2 t; t.x = a; t.y = b;
  __hip_bfloat162 h = __float22bfloat162_rn(t);
  return *(unsigned*)&h;
}
__device__ __forceinline__ float gelu_fast(float x) {
  float x3 = x * x * x;
  float y2 = 1.5957691216f * (x + 0.044715f * x3);
  float e = __expf(y2);
  return x * e / (e + 1.0f);
}
__device__ __forceinline__ void gload16(const short* g, short* l) {
  __builtin_amdgcn_global_load_lds((const __attribute__((address_space(1))) void*)g,
                                   (__attribute__((address_space(3))) void*)l, 16, 0, 0);
}

// ---------------- LayerNorm (fp32 in -> bf16 out), one block per row, C=512
__launch_bounds__(256)
__global__ void ln_kernel(const float* __restrict__ x, const float* __restrict__ g,
                          const float* __restrict__ b, short* __restrict__ out)
{
  int r = blockIdx.x;
  int tid = threadIdx.x;
  float2 v = ((const float2*)(x + (size_t)r * CDIM))[tid];
  float s = v.x + v.y, s2 = v.x * v.x + v.y * v.y;
#pragma unroll
  for (int m = 1; m < 64; m <<= 1) { s += __shfl_xor(s, m); s2 += __shfl_xor(s2, m); }
  __shared__ float red[8];
  int wave = tid >> 6;
  if ((tid & 63) == 0) { red[wave] = s; red[4 + wave] = s2; }
  __syncthreads();
  s  = red[0] + red[1] + red[2] + red[3];
  s2 = red[4] + red[5] + red[6] + red[7];
  float mean = s * (1.0f / CDIM);
  float var  = s2 * (1.0f / CDIM) - mean * mean;
  float inv  = rsqrtf(var + 1e-5f);
  float2 gg = ((const float2*)g)[tid];
  float2 bb = ((const float2*)b)[tid];
  short2 o;
  o.x = f2b((v.x - mean) * inv * gg.x + bb.x);
  o.y = f2b((v.y - mean) * inv * gg.y + bb.y);
  *((short2*)(out + (size_t)r * CDIM + 2 * tid)) = o;
}

// ---------------- batched transpose+convert: W[K][N] f32 -> Wt[N][K] bf16
struct TcvtDesc {
  const float* src[14];
  short* dst[14];
  int K[14], N[14], nblk[14];
};
__launch_bounds__(256)
__global__ void tcvt_all(TcvtDesc d)
{
  int blk = blockIdx.x, wi = 0;
  while (blk >= d.nblk[wi]) { blk -= d.nblk[wi]; wi++; }
  const float* __restrict__ W = d.src[wi];
  short* __restrict__ Wt = d.dst[wi];
  int K = d.K[wi], N = d.N[wi];
  __shared__ float t[32][33];
  int nbk = K >> 5;
  int bk = blk % nbk, bn = blk / nbk;
  int cx = threadIdx.x & 31, cy = threadIdx.x >> 5;
#pragma unroll
  for (int i = 0; i < 4; i++)
    t[cy + 8 * i][cx] = W[(size_t)(bk * 32 + cy + 8 * i) * N + bn * 32 + cx];
  __syncthreads();
#pragma unroll
  for (int i = 0; i < 4; i++)
    Wt[(size_t)(bn * 32 + cy + 8 * i) * K + bk * 32 + cx] = f2b(t[cx][cy + 8 * i]);
}

// ================= 256x256 4-phase GEMM (BK=64, 8 waves, counted vmcnt) ======
// A-LDS [buf][half(row)][128][64] swz slot^(row&7); B-LDS [buf][kk(K-half)][256][32]
// swz slot^((row>>1)&3). Stagger per tile t: ph0->B0(t+1), ph1->A0, ph2->A1,
// ph3->B1. Waits: vmcnt(4)@ph0, vmcnt(6)@ph2 (never 0 in main loop).
// EPI: 0 = bf16 (+softmax per 64-chunk where col<smLimit), 1 = gelu bf16.
template<int EPI>
__launch_bounds__(512, 2)
__global__ void gemm256(const short* __restrict__ A, const short* __restrict__ Bt,
                        const float* __restrict__ bias, void* __restrict__ outp,
                        int M, int N, int K, int smLimit)
{
  __shared__ short As[2 * 16384];
  __shared__ short Bs[2 * 16384];
  int tid = threadIdx.x, lane = tid & 63, wave = tid >> 6;
  int l15 = lane & 15, g = lane >> 4;
  int wr = wave >> 2, wn = wave & 3;
  int nbn = N >> 8;
  int per = gridDim.x >> 3;
  int wg = (blockIdx.x & 7) * per + (blockIdx.x >> 3);
  int bm = wg / nbn, bn = wg % nbn;
  f32x4 acc[8][4] = {};

  // staging sources: chunks c0 = wave*128+lane, c1 = c0+64 per half
  int asl = ((lane & 7) ^ (lane >> 3)) * 8;          // A inverse-swizzled col slot
  int bsl = ((lane & 3) ^ ((lane >> 3) & 3)) * 8;    // B inverse-swizzled col slot
  const short* gA0 = A  + (size_t)(bm * 256 + wave * 16 + (lane >> 3)) * K + asl;
  const short* gB0 = Bt + (size_t)(bn * 256 + wave * 32 + (lane >> 2)) * K + bsl;
  const size_t a1off = (size_t)8 * K;
  const size_t b1off = (size_t)16 * K;
  const size_t ah1   = (size_t)128 * K;
  short* lAbase = As + wave * 1024;
  short* lBbase = Bs + wave * 1024;

  // read offsets
  int aswz0 = (g ^ (l15 & 7)) * 8;
  int aswz1 = ((4 + g) ^ (l15 & 7)) * 8;
  int arow  = wr * 8192 + l15 * 64;
  int brow  = (wn * 64 + l15) * 32 + (g ^ ((l15 >> 1) & 3)) * 8;

  short8 af[4], bfr[4];
  int NT = K >> 6;

#define STGA(buf, h, kt) { \
    gload16(gA0 + ((h) ? ah1 : 0) + (kt), lAbase + (buf) * 16384 + (h) * 8192); \
    gload16(gA0 + ((h) ? ah1 : 0) + a1off + (kt), lAbase + (buf) * 16384 + (h) * 8192 + 512); }
#define STGB(buf, kk, kt) { \
    gload16(gB0 + (kt) + (kk) * 32, lBbase + (buf) * 16384 + (kk) * 8192); \
    gload16(gB0 + (kt) + b1off + (kk) * 32, lBbase + (buf) * 16384 + (kk) * 8192 + 512); }
#define RDB(buf, kk) { \
    const short* bp = Bs + (buf) * 16384 + (kk) * 8192 + brow; \
    bfr[0] = *(const short8*)(bp);        bfr[1] = *(const short8*)(bp + 512); \
    bfr[2] = *(const short8*)(bp + 1024); bfr[3] = *(const short8*)(bp + 1536); }
#define RDA(buf, mh, sw) { \
    const short* ap = As + (buf) * 16384 + arow + (mh) * 4096 + (sw); \
    af[0] = *(const short8*)(ap);        af[1] = *(const short8*)(ap + 1024); \
    af[2] = *(const short8*)(ap + 2048); af[3] = *(const short8*)(ap + 3072); }
#define MFMAQ(mh) { \
    __builtin_amdgcn_s_setprio(1); \
    _Pragma("unroll") for (int j = 0; j < 4; j++) \
      _Pragma("unroll") for (int n = 0; n < 4; n++) \
        acc[(mh) * 4 + j][n] = __builtin_amdgcn_mfma_f32_16x16x32_bf16(bfr[n], af[j], acc[(mh) * 4 + j][n], 0, 0, 0); \
    __builtin_amdgcn_s_setprio(0); }

  // prologue: tile 0, order B0,A0,A1,B1 (matches steady-state issue order)
  STGB(0, 0, 0); STGA(0, 0, 0); STGA(0, 1, 0); STGB(0, 1, 0);

  for (int t = 0; t < NT - 1; ++t) {
    int buf = t & 1, nb_ = buf ^ 1;
    int kt = (t + 1) << 6;
    // ph0: quadrant kk0/mh0
    STGB(nb_, 0, kt);
    asm volatile("s_waitcnt vmcnt(4)" ::: "memory");
    __builtin_amdgcn_s_barrier(); __builtin_amdgcn_sched_barrier(0);
    RDB(buf, 0); RDA(buf, 0, aswz0);
    MFMAQ(0);
    // ph1: kk0/mh1
    STGA(nb_, 0, kt);
    __builtin_amdgcn_s_barrier(); __builtin_amdgcn_sched_barrier(0);
    RDA(buf, 1, aswz0);
    MFMAQ(1);
    // ph2: kk1/mh0
    STGA(nb_, 1, kt);
    asm volatile("s_waitcnt vmcnt(6)" ::: "memory");
    __builtin_amdgcn_s_barrier(); __builtin_amdgcn_sched_barrier(0);
    RDB(buf, 1); RDA(buf, 0, aswz1);
    MFMAQ(0);
    // ph3: kk1/mh1
    STGB(nb_, 1, kt);
    __builtin_amdgcn_s_barrier(); __builtin_amdgcn_sched_barrier(0);
    RDA(buf, 1, aswz1);
    MFMAQ(1);
  }
  { // peeled last tile (no staging; vmcnt drains allowed here only)
    int buf = (NT - 1) & 1;
    asm volatile("s_waitcnt vmcnt(2)" ::: "memory");
    __builtin_amdgcn_s_barrier(); __builtin_amdgcn_sched_barrier(0);
    RDB(buf, 0); RDA(buf, 0, aswz0); MFMAQ(0);
    RDA(buf, 1, aswz0); MFMAQ(1);
    asm volatile("s_waitcnt vmcnt(0)" ::: "memory");
    __builtin_amdgcn_s_barrier(); __builtin_amdgcn_sched_barrier(0);
    RDB(buf, 1); RDA(buf, 0, aswz1); MFMAQ(0);
    RDA(buf, 1, aswz1); MFMAQ(1);
  }
#undef STGA
#undef STGB
#undef RDB
#undef RDA
#undef MFMAQ

  int row0 = bm * 256 + wr * 128, col0 = bn * 256 + wn * 64;
#pragma unroll
  for (int n = 0; n < 4; n++) {
    f32x4 bz = *(const f32x4*)(bias + col0 + n * 16 + g * 4);
#pragma unroll
    for (int m = 0; m < 8; m++)
#pragma unroll
      for (int r = 0; r < 4; r++) acc[m][n][r] += bz[r];
  }
  if (EPI == 0 && col0 < smLimit) {
#pragma unroll
    for (int m = 0; m < 8; m++) {
      float mx = acc[m][0][0];
#pragma unroll
      for (int n = 0; n < 4; n++)
#pragma unroll
        for (int r = 0; r < 4; r++) mx = fmaxf(mx, acc[m][n][r]);
      mx = fmaxf(mx, __shfl_xor(mx, 16));
      mx = fmaxf(mx, __shfl_xor(mx, 32));
      float s = 0.0f;
#pragma unroll
      for (int n = 0; n < 4; n++)
#pragma unroll
        for (int r = 0; r < 4; r++) {
          float e = __expf(acc[m][n][r] - mx);
          acc[m][n][r] = e; s += e;
        }
      s += __shfl_xor(s, 16);
      s += __shfl_xor(s, 32);
      float inv = 1.0f / s;
#pragma unroll
      for (int n = 0; n < 4; n++)
#pragma unroll
        for (int r = 0; r < 4; r++) acc[m][n][r] *= inv;
    }
  }
  if (EPI == 1) {
#pragma unroll
    for (int m = 0; m < 8; m++)
#pragma unroll
      for (int n = 0; n < 4; n++)
#pragma unroll
        for (int r = 0; r < 4; r++) acc[m][n][r] = gelu_fast(acc[m][n][r]);
  }
#pragma unroll
  for (int m = 0; m < 8; m++) {
    int row = row0 + m * 16 + l15;
#pragma unroll
    for (int n = 0; n < 4; n++) {
      size_t base = (size_t)row * N + col0 + n * 16 + g * 4;
      uint2 u;
      u.x = pk2(acc[m][n][0], acc[m][n][1]);
      u.y = pk2(acc[m][n][2], acc[m][n][3]);
      *(uint2*)((unsigned short*)outp + base) = u;
    }
  }
}

// ---------------- 128x128 GEMM (round-4 proven): EPI 0=bf16(+SM<smLimit), 2=res f32
enum { EPI_B_BF16 = 0, EPI_B_RES_F32 = 2 };

template<int EPI>
__launch_bounds__(256)
__global__ void gemm_bt(const short* __restrict__ A, const short* __restrict__ Bt,
                        const float* __restrict__ bias, const float* __restrict__ resid,
                        void* __restrict__ outp, int M, int N, int K, int smLimit)
{
  __shared__ short As[2 * 4096];
  __shared__ short Bs[2 * 4096];
  int tid = threadIdx.x;
  int lane = tid & 63, wave = tid >> 6;
  int l15 = lane & 15, g = lane >> 4;
  int nbn = N >> 7;
  int per = gridDim.x >> 3;
  int wg = (blockIdx.x & 7) * per + (blockIdx.x >> 3);
  int bm = wg / nbn, bn = wg % nbn;
  int wr = wave >> 1, wc = wave & 1;
  f32x4 acc[4][4] = {};

  int srcslot = (lane & 3) ^ ((lane >> 3) & 3);
  const short* gA0 = A  + (size_t)(bm * 128 + wave * 16 + (lane >> 2)) * K + srcslot * 8;
  const short* gB0 = Bt + (size_t)(bn * 128 + wave * 16 + (lane >> 2)) * K + srcslot * 8;
  const short* gA1 = gA0 + (size_t)64 * K;
  const short* gB1 = gB0 + (size_t)64 * K;
  short* lA0 = As + wave * 512;
  short* lA1 = As + wave * 512 + 2048;
  short* lB0 = Bs + wave * 512;
  short* lB1 = Bs + wave * 512 + 2048;
  int rslot = (g ^ ((l15 >> 1) & 3)) * 8;
  const short* ra = As + (wr * 64 + l15) * 32 + rslot;
  const short* rb = Bs + (wc * 64 + l15) * 32 + rslot;

  gload16(gA0, lA0); gload16(gA1, lA1);
  gload16(gB0, lB0); gload16(gB1, lB1);

  int cur = 0;
  for (int kt = 0; kt < K; kt += 32) {
    if (kt + 32 < K) {
      int nb_ = cur ^ 1;
      gload16(gA0 + kt + 32, lA0 + nb_ * 4096);
      gload16(gA1 + kt + 32, lA1 + nb_ * 4096);
      gload16(gB0 + kt + 32, lB0 + nb_ * 4096);
      gload16(gB1 + kt + 32, lB1 + nb_ * 4096);
      asm volatile("s_waitcnt vmcnt(4)" ::: "memory");
    } else {
      asm volatile("s_waitcnt vmcnt(0)" ::: "memory");
    }
    __builtin_amdgcn_s_barrier();
    __builtin_amdgcn_sched_barrier(0);
    const short* rac = ra + cur * 4096;
    const short* rbc = rb + cur * 4096;
    short8 af[4], bfr[4];
#pragma unroll
    for (int m = 0; m < 4; m++) af[m]  = *(const short8*)(rac + m * 512);
#pragma unroll
    for (int n = 0; n < 4; n++) bfr[n] = *(const short8*)(rbc + n * 512);
    __builtin_amdgcn_s_setprio(1);
#pragma unroll
    for (int m = 0; m < 4; m++)
#pragma unroll
      for (int n = 0; n < 4; n++)
        acc[m][n] = __builtin_amdgcn_mfma_f32_16x16x32_bf16(bfr[n], af[m], acc[m][n], 0, 0, 0);
    __builtin_amdgcn_s_setprio(0);
    __builtin_amdgcn_sched_barrier(0);
    __builtin_amdgcn_s_barrier();
    cur ^= 1;
  }

  int row0 = bm * 128 + wr * 64, col0 = bn * 128 + wc * 64;
#pragma unroll
  for (int n = 0; n < 4; n++) {
    f32x4 bz = *(const f32x4*)(bias + col0 + n * 16 + g * 4);
#pragma unroll
    for (int m = 0; m < 4; m++)
#pragma unroll
      for (int r = 0; r < 4; r++)
        acc[m][n][r] += bz[r];
  }
  if (EPI == EPI_B_BF16 && col0 < smLimit) {
#pragma unroll
    for (int m = 0; m < 4; m++) {
      float mx = acc[m][0][0];
#pragma unroll
      for (int n = 0; n < 4; n++)
#pragma unroll
        for (int r = 0; r < 4; r++) mx = fmaxf(mx, acc[m][n][r]);
      mx = fmaxf(mx, __shfl_xor(mx, 16));
      mx = fmaxf(mx, __shfl_xor(mx, 32));
      float s = 0.0f;
#pragma unroll
      for (int n = 0; n < 4; n++)
#pragma unroll
        for (int r = 0; r < 4; r++) {
          float e = __expf(acc[m][n][r] - mx);
          acc[m][n][r] = e; s += e;
        }
      s += __shfl_xor(s, 16);
      s += __shfl_xor(s, 32);
      float inv = 1.0f / s;
#pragma unroll
      for (int n = 0; n < 4; n++)
#pragma unroll
        for (int r = 0; r < 4; r++) acc[m][n][r] *= inv;
    }
  }
#pragma unroll
  for (int m = 0; m < 4; m++) {
    int row = row0 + m * 16 + l15;
#pragma unroll
    for (int n = 0; n < 4; n++) {
      size_t base = (size_t)row * N + col0 + n * 16 + g * 4;
      if (EPI == EPI_B_RES_F32) {
        f32x4 rv = *(const f32x4*)(resid + base);
        f32x4 o;
#pragma unroll
        for (int r = 0; r < 4; r++) o[r] = rv[r] + acc[m][n][r];
        *(f32x4*)((float*)outp + base) = o;
      } else {
        uint2 u;
        u.x = pk2(acc[m][n][0], acc[m][n][1]);
        u.y = pk2(acc[m][n][2], acc[m][n][3]);
        *(uint2*)((unsigned short*)outp + base) = u;
      }
    }
  }
}

// ---------------- ctx += k^T v per (b,h); grid = 32*parts, atomics into zeroed ctx
#define LDC 40
__launch_bounds__(256)
__global__ void ctx_kernel(const short* __restrict__ k, const short* __restrict__ v,
                           float* __restrict__ ctx, int T, int parts, int SD)
{
  __shared__ short kT[4][64 * LDC];
  __shared__ short vT[4][64 * LDC];
  int bh = blockIdx.x & 31, part = blockIdx.x >> 5;
  int b = bh >> 3, h = bh & 7;
  int tid = threadIdx.x, lane = tid & 63, wave = tid >> 6;
  int l15 = lane & 15, g = lane >> 4;
  int tlen = T / (4 * parts);
  int tbeg = (part * 4 + wave) * tlen;
  f32x4 acc[4][4] = {};
  short* myK = kT[wave];
  short* myV = vT[wave];
  for (int t0 = tbeg; t0 < tbeg + tlen; t0 += 32) {
#pragma unroll
    for (int j = 0; j < 4; j++) {
      int c = lane + j * 64;
      int r = c >> 3, d0 = (c & 7) * 8;
      short8 kv = *(const short8*)(k + (size_t)(b * T + t0 + r) * SD + h * 64 + d0);
      short8 vv = *(const short8*)(v + (size_t)(b * T + t0 + r) * SD + h * 64 + d0);
#pragma unroll
      for (int i = 0; i < 8; i++) {
        myK[(d0 + i) * LDC + r] = kv[i];
        myV[(d0 + i) * LDC + r] = vv[i];
      }
    }
    __syncthreads();
    short8 af[4], bfr[4];
#pragma unroll
    for (int m = 0; m < 4; m++) af[m]  = *(const short8*)(myK + (m * 16 + l15) * LDC + g * 8);
#pragma unroll
    for (int n = 0; n < 4; n++) bfr[n] = *(const short8*)(myV + (n * 16 + l15) * LDC + g * 8);
#pragma unroll
    for (int m = 0; m < 4; m++)
#pragma unroll
      for (int n = 0; n < 4; n++)
        acc[m][n] = __builtin_amdgcn_mfma_f32_16x16x32_bf16(af[m], bfr[n], acc[m][n], 0, 0, 0);
    __syncthreads();
  }
  float* cp = ctx + (size_t)bh * 64 * 64;
#pragma unroll
  for (int m = 0; m < 4; m++)
#pragma unroll
    for (int n = 0; n < 4; n++)
#pragma unroll
      for (int r = 0; r < 4; r++)
        atomicAdd(cp + (m * 16 + g * 4 + r) * 64 + (n * 16 + l15), acc[m][n][r]);
}

// ---------------- column sums of softmaxed k per (b,h): ksum[bh][64]
__launch_bounds__(256)
__global__ void colsum_kernel(const short* __restrict__ k, float* __restrict__ ksum,
                              int T, int SD)
{
  int part = blockIdx.x & 7, bh = blockIdx.x >> 3;
  int b = bh >> 3, h = bh & 7;
  int d = threadIdx.x & 63, tq = threadIdx.x >> 6;
  int tlen = T >> 3, t0 = part * tlen;
  float s = 0.0f;
  for (int t = t0 + tq; t < t0 + tlen; t += 4)
    s += b2f(k[(size_t)(b * T + t) * SD + h * 64 + d]);
  atomicAdd(&ksum[bh * 64 + d], s);
}

// ---------------- out[t,:] = q[t,:] + sum_br dinv(t) * (q[t,:] @ ctx[br])
#define LQ 72
__launch_bounds__(256)
__global__ void qctx_kernel(const short* __restrict__ q,
                            const float* __restrict__ ctx,   // [nb][32][64][64]
                            const float* __restrict__ ksum,  // [nb][32][64]
                            short* __restrict__ outp, int T, int nb, int SD)
{
  __shared__ short qs[128 * LQ];
  __shared__ short cT[2][64 * LQ];
  __shared__ float dls[2][128];
  int ntb = T >> 7;
  int bh = blockIdx.x / ntb, tq = blockIdx.x % ntb;
  int b = bh >> 3, h = bh & 7;
  int tid = threadIdx.x, lane = tid & 63, wave = tid >> 6;
  int l15 = lane & 15, g = lane >> 4;
  size_t qbase = (size_t)(b * T + tq * 128) * SD + h * 64;
  size_t obase = (size_t)(b * T + tq * 128) * CDIM + h * 64;

#pragma unroll
  for (int j = 0; j < 4; j++) {
    int c = tid + j * 256;
    int r = c >> 3, d0 = (c & 7) * 8;
    *(short8*)(qs + r * LQ + d0) = *(const short8*)(q + qbase + (size_t)r * SD + d0);
  }
  for (int br = 0; br < nb; br++) {
    const float* cp = ctx + ((size_t)br * 32 + bh) * 4096;
#pragma unroll
    for (int j = 0; j < 16; j++) {
      int e2 = tid + j * 256;
      int dd = e2 >> 6, ee = e2 & 63;
      cT[br][ee * LQ + dd] = f2b(cp[e2]);
    }
  }
  __syncthreads();

  int r0 = wave * 32;
  for (int br = 0; br < nb; br++) {
    int row = r0 + (lane >> 1);
    int dbase = (lane & 1) * 32;
    const float* kp = ksum + ((size_t)br * 32 + bh) * 64 + dbase;
    float s = 0.0f;
#pragma unroll
    for (int d = 0; d < 32; d++)
      s += b2f(qs[row * LQ + dbase + d]) * kp[d];
    s += __shfl_xor(s, 1);
    if (!(lane & 1)) dls[br][row] = 1.0f / fmaxf(s, 1e-9f);
  }

  short8 af[2][2];
#pragma unroll
  for (int m = 0; m < 2; m++)
#pragma unroll
    for (int kk = 0; kk < 2; kk++)
      af[m][kk] = *(const short8*)(qs + (r0 + m * 16 + l15) * LQ + kk * 32 + g * 8);

  float ofin[2][4][4];
#pragma unroll
  for (int m = 0; m < 2; m++)
#pragma unroll
    for (int n = 0; n < 4; n++)
#pragma unroll
      for (int r = 0; r < 4; r++)
        ofin[m][n][r] = b2f(qs[(r0 + m * 16 + g * 4 + r) * LQ + n * 16 + l15]);

  for (int br = 0; br < nb; br++) {
    f32x4 acc[2][4] = {};
#pragma unroll
    for (int kk = 0; kk < 2; kk++) {
      short8 bfr[4];
#pragma unroll
      for (int n = 0; n < 4; n++)
        bfr[n] = *(const short8*)(cT[br] + (n * 16 + l15) * LQ + kk * 32 + g * 8);
#pragma unroll
      for (int m = 0; m < 2; m++)
#pragma unroll
        for (int n = 0; n < 4; n++)
          acc[m][n] = __builtin_amdgcn_mfma_f32_16x16x32_bf16(af[m][kk], bfr[n], acc[m][n], 0, 0, 0);
    }
#pragma unroll
    for (int m = 0; m < 2; m++)
#pragma unroll
      for (int n = 0; n < 4; n++)
#pragma unroll
        for (int r = 0; r < 4; r++)
          ofin[m][n][r] += dls[br][r0 + m * 16 + g * 4 + r] * acc[m][n][r];
  }

#pragma unroll
  for (int m = 0; m < 2; m++)
#pragma unroll
    for (int n = 0; n < 4; n++)
#pragma unroll
      for (int r = 0; r < 4; r++) {
        int row = r0 + m * 16 + g * 4 + r;
        int col = n * 16 + l15;
        outp[obase + (size_t)row * CDIM + col] = f2b(ofin[m][n][r]);
      }
}

extern "C" void kernel_launch(void* const* d_in, const int* in_sizes, int n_in,
                              void* d_out, int out_size, void* d_ws, size_t ws_size,
                              hipStream_t stream)
{
  (void)in_sizes; (void)n_in; (void)out_size; (void)ws_size;
  const float* x     = (const float*)d_in[0];
  const float* y0    = (const float*)d_in[1];
  const float* y1    = (const float*)d_in[2];
  const float* ln1g  = (const float*)d_in[3];
  const float* ln1b  = (const float*)d_in[4];
  const float* ln20g = (const float*)d_in[5];
  const float* ln20b = (const float*)d_in[6];
  const float* ln21g = (const float*)d_in[7];
  const float* ln21b = (const float*)d_in[8];
  const float* ln3g  = (const float*)d_in[9];
  const float* ln3b  = (const float*)d_in[10];
  const float* ln4g  = (const float*)d_in[11];
  const float* ln4b  = (const float*)d_in[12];
  const float* ln5g  = (const float*)d_in[13];
  const float* ln5b  = (const float*)d_in[14];
  const float* caqw  = (const float*)d_in[15];
  const float* caqb  = (const float*)d_in[16];
  const float* cak0w = (const float*)d_in[17];
  const float* cak0b = (const float*)d_in[18];
  const float* cav0w = (const float*)d_in[19];
  const float* cav0b = (const float*)d_in[20];
  const float* cak1w = (const float*)d_in[21];
  const float* cak1b = (const float*)d_in[22];
  const float* cav1w = (const float*)d_in[23];
  const float* cav1b = (const float*)d_in[24];
  const float* capw  = (const float*)d_in[25];
  const float* capb  = (const float*)d_in[26];
  const float* saqw  = (const float*)d_in[27];
  const float* saqb  = (const float*)d_in[28];
  const float* sakw  = (const float*)d_in[29];
  const float* sakb  = (const float*)d_in[30];
  const float* savw  = (const float*)d_in[31];
  const float* savb  = (const float*)d_in[32];
  const float* sapw  = (const float*)d_in[33];
  const float* sapb  = (const float*)d_in[34];
  const float* m1w1  = (const float*)d_in[35];
  const float* m1b1  = (const float*)d_in[36];
  const float* m1w2  = (const float*)d_in[37];
  const float* m1b2  = (const float*)d_in[38];
  const float* m2w1  = (const float*)d_in[39];
  const float* m2b1  = (const float*)d_in[40];
  const float* m2w2  = (const float*)d_in[41];
  const float* m2b2  = (const float*)d_in[42];
  float* xout = (float*)d_out;

  char* p = (char*)d_ws;
  size_t off = 0;
  auto take = [&](size_t bytes) {
    char* r = p + off;
    off += (bytes + 255) & ~(size_t)255;
    return r;
  };
  const size_t W512 = (size_t)512 * 512 * 2;
  const size_t WMLP = (size_t)2048 * 512 * 2;
  short* wt_caq   = (short*)take(W512);
  short* wt_cakv0 = (short*)take(2 * W512);       // [k;v] 1024x512
  short* wt_cakv1 = (short*)take(2 * W512);
  short* wt_cap   = (short*)take(W512);
  short* wt_saqkv = (short*)take(3 * W512);       // [q;k;v] 1536x512
  short* wt_sap   = (short*)take(W512);
  short* wt_m1w1  = (short*)take(WMLP);
  short* wt_m1w2  = (short*)take(WMLP);
  short* wt_m2w1  = (short*)take(WMLP);
  short* wt_m2w2  = (short*)take(WMLP);
  float* b_saqkv  = (float*)take(1536 * 4);
  float* b_cakv0  = (float*)take(1024 * 4);
  float* b_cakv1  = (float*)take(1024 * 4);
  short* xn   = (short*)take((size_t)16384 * 512 * 2);
  short* bufD = (short*)take((size_t)16384 * 512 * 2);
  short* big  = (short*)take((size_t)16384 * 1536 * 2);   // CA: q@0, kv@+8M shorts; SA: qkv
  short* h1   = (short*)take((size_t)16384 * 2048 * 2);
  float* ksum = (float*)take((size_t)2 * 32 * 64 * 4);
  float* ctxb = (float*)take((size_t)2 * 32 * 64 * 64 * 4);

  short* q_ca  = big;
  short* kv_ca = big + (size_t)8 * 1024 * 1024;
  short* qkv   = big;

  const int MQ  = NBATCH * TQD;   // 16384
  const int MKV = NBATCH * TBD;   // 8192

  // ---- weight transpose+convert (single batched launch) ----
  {
    TcvtDesc d;
    const float* srcs[14] = {caqw, cak0w, cav0w, cak1w, cav1w, capw,
                             saqw, sakw, savw, sapw, m1w1, m1w2, m2w1, m2w2};
    short* dsts[14] = {wt_caq, wt_cakv0, wt_cakv0 + 512 * 512,
                       wt_cakv1, wt_cakv1 + 512 * 512, wt_cap,
                       wt_saqkv, wt_saqkv + 512 * 512, wt_saqkv + 2 * 512 * 512, wt_sap,
                       wt_m1w1, wt_m1w2, wt_m2w1, wt_m2w2};
    int Ks[14] = {512,512,512,512,512,512,512,512,512,512, 512,2048,512,2048};
    int Ns[14] = {512,512,512,512,512,512,512,512,512,512, 2048,512,2048,512};
    int total = 0;
    for (int i = 0; i < 14; i++) {
      d.src[i] = srcs[i]; d.dst[i] = dsts[i]; d.K[i] = Ks[i]; d.N[i] = Ns[i];
      d.nblk[i] = (Ks[i] >> 5) * (Ns[i] >> 5);
      total += d.nblk[i];
    }
    tcvt_all<<<total, 256, 0, stream>>>(d);
  }
  // ---- bias concats (device-to-device async copies; capture-safe) ----
  hipMemcpyAsync(b_saqkv,        saqb,  512 * 4, hipMemcpyDeviceToDevice, stream);
  hipMemcpyAsync(b_saqkv + 512,  sakb,  512 * 4, hipMemcpyDeviceToDevice, stream);
  hipMemcpyAsync(b_saqkv + 1024, savb,  512 * 4, hipMemcpyDeviceToDevice, stream);
  hipMemcpyAsync(b_cakv0,        cak0b, 512 * 4, hipMemcpyDeviceToDevice, stream);
  hipMemcpyAsync(b_cakv0 + 512,  cav0b, 512 * 4, hipMemcpyDeviceToDevice, stream);
  hipMemcpyAsync(b_cakv1,        cak1b, 512 * 4, hipMemcpyDeviceToDevice, stream);
  hipMemcpyAsync(b_cakv1 + 512,  cav1b, 512 * 4, hipMemcpyDeviceToDevice, stream);

  // ---- cross-attention ----
  ln_kernel<<<MQ, 256, 0, stream>>>(x, ln1g, ln1b, xn);
  gemm_bt<0><<<512, 256, 0, stream>>>(xn, wt_caq, caqb, nullptr, q_ca, MQ, 512, 512, 512);
  hipMemsetAsync(ksum, 0, (size_t)2 * 32 * 64 * 4, stream);
  hipMemsetAsync(ctxb, 0, (size_t)2 * 32 * 64 * 64 * 4, stream);
  for (int br = 0; br < 2; br++) {
    const float* yy = br ? y1 : y0;
    const float* lg = br ? ln21g : ln20g;
    const float* lb = br ? ln21b : ln20b;
    const short* wk = br ? wt_cakv1 : wt_cakv0;
    const float* bk = br ? b_cakv1 : b_cakv0;
    ln_kernel<<<MKV, 256, 0, stream>>>(yy, lg, lb, bufD);
    gemm_bt<0><<<512, 256, 0, stream>>>(bufD, wk, bk, nullptr, kv_ca, MKV, 1024, 512, 512);
    colsum_kernel<<<256, 256, 0, stream>>>(kv_ca, ksum + (size_t)br * 2048, TBD, 1024);
    ctx_kernel<<<256, 256, 0, stream>>>(kv_ca, kv_ca + 512,
                                        ctxb + (size_t)br * 32 * 4096, TBD, 8, 1024);
  }
  qctx_kernel<<<32 * (TQD / 128), 256, 0, stream>>>(q_ca, ctxb, ksum, bufD, TQD, 2, 512);
  gemm_bt<2><<<512, 256, 0, stream>>>(bufD, wt_cap, capb, x, xout, MQ, 512, 512, 0);

  // ---- MLP 1 ----
  ln_kernel<<<MQ, 256, 0, stream>>>(xout, ln3g, ln3b, xn);
  gemm256<1><<<512, 512, 0, stream>>>(xn, wt_m1w1, m1b1, h1, MQ, 2048, 512, 0);
  gemm_bt<2><<<512, 256, 0, stream>>>(h1, wt_m1w2, m1b2, xout, xout, MQ, 512, 2048, 0);

  // ---- self-attention (fused q|k|v projection) ----
  ln_kernel<<<MQ, 256, 0, stream>>>(xout, ln4g, ln4b, xn);
  gemm256<0><<<384, 512, 0, stream>>>(xn, wt_saqkv, b_saqkv, qkv, MQ, 1536, 512, 1024);
  hipMemsetAsync(ksum, 0, (size_t)32 * 64 * 4, stream);
  hipMemsetAsync(ctxb, 0, (size_t)32 * 64 * 64 * 4, stream);
  colsum_kernel<<<256, 256, 0, stream>>>(qkv + 512, ksum, TQD, 1536);
  ctx_kernel<<<256, 256, 0, stream>>>(qkv + 512, qkv + 1024, ctxb, TQD, 8, 1536);
  qctx_kernel<<<32 * (TQD / 128), 256, 0, stream>>>(qkv, ctxb, ksum, bufD, TQD, 1, 1536);
  gemm_bt<2><<<512, 256, 0, stream>>>(bufD, wt_sap, sapb, xout, xout, MQ, 512, 512, 0);

  // ---- MLP 2 ----
  ln_kernel<<<MQ, 256, 0, stream>>>(xout, ln5g, ln5b, xn);
  gemm256<1><<<512, 512, 0, stream>>>(xn, wt_m2w1, m2b1, h1, MQ, 2048, 512, 0);
  gemm_bt<2><<<512, 256, 0, stream>>>(h1, wt_m2w2, m2b2, xout, xout, MQ, 512, 2048, 0);
}